// Round 1
// baseline (3328.640 us; speedup 1.0000x reference)
//
#include <hip/hip_runtime.h>
#include <hip/hip_bf16.h>

#define NN 50000
#define NE 800000
#define DD 128
#define LN_EPS 1e-5f

__device__ __forceinline__ float leakyf(float x){ return x > 0.f ? x : 0.05f*x; }

// ---------------------------------------------------------------------------
// Generic row-wise 3-layer MLP + LayerNorm. Block = 128 threads (one col per
// thread), ROWS=16 rows per block. If SCATTER, atomically adds the LN'd row
// into out[sidx[row]*128 + col] (used for the edge->src scatter-sum).
// ---------------------------------------------------------------------------
template<int IN_W, bool SCATTER>
__global__ __launch_bounds__(128)
void mlp_ln_kernel(const float* __restrict__ x, int nrows,
                   const float* __restrict__ W1, const float* __restrict__ b1,
                   const float* __restrict__ W2, const float* __restrict__ b2,
                   const float* __restrict__ W3, const float* __restrict__ b3,
                   const float* __restrict__ g, const float* __restrict__ bb,
                   float* __restrict__ out, const int* __restrict__ sidx)
{
  constexpr int ROWS = 16;
  constexpr int XPAD = (IN_W == 128) ? 132 : IN_W;   // pad big tiles to break bank conflicts
  __shared__ __align__(16) float xs[ROWS][XPAD];
  __shared__ __align__(16) float hb[2][ROWS][132];
  __shared__ float mrow[ROWS], srow_[ROWS];
  __shared__ int sidx_s[ROWS];

  const int row0 = blockIdx.x * ROWS;
  const int col  = threadIdx.x;   // 0..127

  for (int t = col; t < ROWS*IN_W; t += 128) {
    int r = t / IN_W, k = t - r*IN_W;
    int gr = row0 + r;
    xs[r][k] = (gr < nrows) ? x[(size_t)gr*IN_W + k] : 0.f;
  }
  if (SCATTER) {
    if (col < ROWS) { int gr = row0 + col; sidx_s[col] = (gr < nrows) ? sidx[gr] : 0; }
  }
  __syncthreads();

  float acc[ROWS];

  // ---- layer 1 (IN_W -> 128), leaky ----
  {
    float bias = b1[col];
    #pragma unroll
    for (int r = 0; r < ROWS; r++) acc[r] = bias;
    for (int k = 0; k < IN_W; k++) {
      float w = W1[k*DD + col];
      #pragma unroll
      for (int r = 0; r < ROWS; r++) acc[r] += xs[r][k] * w;
    }
    #pragma unroll
    for (int r = 0; r < ROWS; r++) hb[0][r][col] = leakyf(acc[r]);
  }
  __syncthreads();

  // ---- layer 2 (128 -> 128), leaky ----
  {
    float bias = b2[col];
    #pragma unroll
    for (int r = 0; r < ROWS; r++) acc[r] = bias;
    for (int kq = 0; kq < DD/4; kq++) {
      float w0 = W2[(4*kq+0)*DD + col];
      float w1 = W2[(4*kq+1)*DD + col];
      float w2 = W2[(4*kq+2)*DD + col];
      float w3 = W2[(4*kq+3)*DD + col];
      #pragma unroll
      for (int r = 0; r < ROWS; r++) {
        const float4 xv = *(const float4*)&hb[0][r][4*kq];
        acc[r] += xv.x*w0 + xv.y*w1 + xv.z*w2 + xv.w*w3;
      }
    }
    #pragma unroll
    for (int r = 0; r < ROWS; r++) hb[1][r][col] = leakyf(acc[r]);
  }
  __syncthreads();

  // ---- layer 3 (128 -> 128), no activation ----
  {
    float bias = b3[col];
    #pragma unroll
    for (int r = 0; r < ROWS; r++) acc[r] = bias;
    for (int kq = 0; kq < DD/4; kq++) {
      float w0 = W3[(4*kq+0)*DD + col];
      float w1 = W3[(4*kq+1)*DD + col];
      float w2 = W3[(4*kq+2)*DD + col];
      float w3 = W3[(4*kq+3)*DD + col];
      #pragma unroll
      for (int r = 0; r < ROWS; r++) {
        const float4 xv = *(const float4*)&hb[1][r][4*kq];
        acc[r] += xv.x*w0 + xv.y*w1 + xv.z*w2 + xv.w*w3;
      }
    }
  }
  __syncthreads();

  // ---- LayerNorm over the 128 cols of each row ----
  #pragma unroll
  for (int r = 0; r < ROWS; r++) hb[0][r][col] = acc[r];
  __syncthreads();
  {
    int r = col >> 3, sub = col & 7;   // 8 threads per row
    float s = 0.f, ss = 0.f;
    for (int c = sub; c < DD; c += 8) { float v = hb[0][r][c]; s += v; ss += v*v; }
    s += __shfl_xor(s, 1);  ss += __shfl_xor(ss, 1);
    s += __shfl_xor(s, 2);  ss += __shfl_xor(ss, 2);
    s += __shfl_xor(s, 4);  ss += __shfl_xor(ss, 4);
    if (sub == 0) {
      float m = s / DD;
      float var = ss / DD - m*m;
      mrow[r]  = m;
      srow_[r] = rsqrtf(var + LN_EPS);
    }
  }
  __syncthreads();

  float gc = g[col], bc = bb[col];
  #pragma unroll
  for (int r = 0; r < ROWS; r++) {
    int gr = row0 + r;
    if (gr >= nrows) continue;
    float v = (acc[r] - mrow[r]) * srow_[r] * gc + bc;
    if (SCATTER) {
      atomicAdd(&out[(size_t)sidx_s[r]*DD + col], v);
    } else {
      out[(size_t)gr*DD + col] = v;
    }
  }
}

// ---------------------------------------------------------------------------
// h = x @ W (+ per-col init vector, used for the folded-BN constant)
// ---------------------------------------------------------------------------
__global__ __launch_bounds__(128)
void gemm128_kernel(const float* __restrict__ x, const float* __restrict__ W,
                    const float* __restrict__ initv, float* __restrict__ out, int nrows)
{
  constexpr int ROWS = 16;
  __shared__ __align__(16) float xs[ROWS][132];
  const int row0 = blockIdx.x * ROWS, col = threadIdx.x;
  for (int t = col; t < ROWS*DD; t += 128) {
    int r = t >> 7, k = t & 127;
    int gr = row0 + r;
    xs[r][k] = (gr < nrows) ? x[(size_t)gr*DD + k] : 0.f;
  }
  __syncthreads();
  float init = initv ? initv[col] : 0.f;
  float acc[ROWS];
  #pragma unroll
  for (int r = 0; r < ROWS; r++) acc[r] = init;
  for (int kq = 0; kq < DD/4; kq++) {
    float w0 = W[(4*kq+0)*DD + col];
    float w1 = W[(4*kq+1)*DD + col];
    float w2 = W[(4*kq+2)*DD + col];
    float w3 = W[(4*kq+3)*DD + col];
    #pragma unroll
    for (int r = 0; r < ROWS; r++) {
      const float4 xv = *(const float4*)&xs[r][4*kq];
      acc[r] += xv.x*w0 + xv.y*w1 + xv.z*w2 + xv.w*w3;
    }
  }
  #pragma unroll
  for (int r = 0; r < ROWS; r++) {
    int gr = row0 + r;
    if (gr < nrows) out[(size_t)gr*DD + col] = acc[r];
  }
}

// ---------------------------------------------------------------------------
// GCN aggregation via dst-CSR. One wave per node; lane handles 2 cols (float2).
// mode 0: out = leaky(agg + bias)          (conv1 -> BN input)
// mode 1: out = resid + (agg + bias)       (conv2 -> residual add)
// ---------------------------------------------------------------------------
__global__ __launch_bounds__(256)
void gcn_agg_kernel(const float* __restrict__ h, const int* __restrict__ rowptr,
                    const int* __restrict__ csr_src, const float* __restrict__ dis,
                    const float* __restrict__ selfco, const float* __restrict__ bias,
                    const float* __restrict__ resid, float* __restrict__ out, int mode)
{
  const int wv = threadIdx.x >> 6, lane = threadIdx.x & 63;
  const int i = blockIdx.x*4 + wv;
  if (i >= NN) return;
  const float2* h2 = (const float2*)h;
  const float di = dis[i];
  const float sc = selfco[i];
  float2 hv = h2[(size_t)i*64 + lane];
  float ax = sc*hv.x, ay = sc*hv.y;
  const int beg = rowptr[i], end = rowptr[i+1];
  for (int j = beg; j < end; j++) {
    int s = csr_src[j];
    float c = dis[s] * di;
    float2 v = h2[(size_t)s*64 + lane];
    ax += c*v.x; ay += c*v.y;
  }
  ax += bias[2*lane]; ay += bias[2*lane+1];
  size_t o = (size_t)i*64 + lane;
  float2 r;
  if (mode == 0) { r.x = leakyf(ax); r.y = leakyf(ay); }
  else { float2 rs = ((const float2*)resid)[o]; r.x = rs.x + ax; r.y = rs.y + ay; }
  ((float2*)out)[o] = r;
}

// ---------------------------------------------------------------------------
// Degree / count histograms
// ---------------------------------------------------------------------------
__global__ void count_kernel(const int* __restrict__ src, const int* __restrict__ dst,
                             int* __restrict__ cnt_src, int* __restrict__ deg_dst)
{
  int e = blockIdx.x*blockDim.x + threadIdx.x;
  if (e < NE) {
    atomicAdd(&cnt_src[src[e]], 1);
    atomicAdd(&deg_dst[dst[e]], 1);
  }
}

__global__ void nodeparams_kernel(const int* __restrict__ deg_dst, const int* __restrict__ cnt_src,
                                  float* __restrict__ dis, float* __restrict__ selfco,
                                  float* __restrict__ invcnt)
{
  int i = blockIdx.x*blockDim.x + threadIdx.x;
  if (i < NN) {
    float d = (float)deg_dst[i] + 1.0f;
    dis[i] = rsqrtf(d);
    selfco[i] = 1.0f / d;
    float c = (float)cnt_src[i];
    invcnt[i] = 1.0f / fmaxf(c, 1.0f);
  }
}

// Single-block exclusive scan of deg -> rowptr (and copy to nextp)
__global__ void scan_kernel(const int* __restrict__ deg, int* __restrict__ rowptr,
                            int* __restrict__ nextp)
{
  const int T = 256;
  int tid = threadIdx.x;
  int chunk = (NN + T - 1) / T;
  int begin = tid*chunk, end = begin + chunk; if (end > NN) end = NN; if (begin > NN) begin = NN;
  int s = 0;
  for (int i = begin; i < end; i++) s += deg[i];
  __shared__ int ps[T];
  ps[tid] = s; __syncthreads();
  for (int off = 1; off < T; off <<= 1) {
    int v = 0;
    if (tid >= off) v = ps[tid - off];
    __syncthreads();
    if (tid >= off) ps[tid] += v;
    __syncthreads();
  }
  int base = (tid == 0) ? 0 : ps[tid-1];
  for (int i = begin; i < end; i++) { rowptr[i] = base; nextp[i] = base; base += deg[i]; }
  if (tid == T-1) rowptr[NN] = base;
}

__global__ void fill_kernel(const int* __restrict__ src, const int* __restrict__ dst,
                            int* __restrict__ nextp, int* __restrict__ csr_src)
{
  int e = blockIdx.x*blockDim.x + threadIdx.x;
  if (e < NE) {
    int pos = atomicAdd(&nextp[dst[e]], 1);
    csr_src[pos] = src[e];
  }
}

// hn += nodesum * invcnt   (scatter-mean finalize)
__global__ void addmean_kernel(float* __restrict__ hn, const float* __restrict__ nodesum,
                               const float* __restrict__ invcnt)
{
  int t = blockIdx.x*blockDim.x + threadIdx.x;
  if (t < NN*DD) {
    int i = t >> 7;
    hn[t] += nodesum[t] * invcnt[i];
  }
}

// ---------------------------------------------------------------------------
// BatchNorm column stats: sums[0..127]=sum, sums[128..255]=sumsq
// ---------------------------------------------------------------------------
__global__ __launch_bounds__(256)
void bn_stats_kernel(const float* __restrict__ y, float* __restrict__ sums)
{
  int col = threadIdx.x & 127, grp = threadIdx.x >> 7;
  float s = 0.f, ss = 0.f;
  for (int i = blockIdx.x*2 + grp; i < NN; i += gridDim.x*2) {
    float v = y[(size_t)i*DD + col];
    s += v; ss += v*v;
  }
  __shared__ float ls[256], lss[256];
  ls[threadIdx.x] = s; lss[threadIdx.x] = ss;
  __syncthreads();
  if (grp == 0) {
    s  = ls[col]  + ls[col+128];
    ss = lss[col] + lss[col+128];
    atomicAdd(&sums[col], s);
    atomicAdd(&sums[DD + col], ss);
  }
}

// Fold BN affine (scale/shift per input feature) into W2:
//   Wf[k][c] = scale[k]*W2[k][c];  cvec[c] = sum_k shift[k]*W2[k][c]
__global__ void bn_fold_kernel(const float* __restrict__ sums, const float* __restrict__ g,
                               const float* __restrict__ b, const float* __restrict__ W2,
                               float* __restrict__ Wf, float* __restrict__ cvec)
{
  int col = threadIdx.x;  // 128 threads
  __shared__ float scale[DD], shift[DD];
  float m = sums[col] / (float)NN;
  float var = sums[DD + col] / (float)NN - m*m;
  float is = rsqrtf(var + LN_EPS);
  float sc = is * g[col];
  scale[col] = sc;
  shift[col] = b[col] - m * sc;
  __syncthreads();
  float c = 0.f;
  for (int k = 0; k < DD; k++) {
    float w = W2[k*DD + col];
    Wf[k*DD + col] = w * scale[k];
    c += shift[k] * w;
  }
  cvec[col] = c;
}

// ---------------------------------------------------------------------------
extern "C" void kernel_launch(void* const* d_in, const int* in_sizes, int n_in,
                              void* d_out, int out_size, void* d_ws, size_t ws_size,
                              hipStream_t stream)
{
  const float* node_feat = (const float*)d_in[0];
  const float* edge_feat = (const float*)d_in[1];
  const int*   edge_index = (const int*)d_in[2];
  const int* src = edge_index;
  const int* dst = edge_index + NE;

  const float* enW1 = (const float*)d_in[3];  const float* enb1 = (const float*)d_in[4];
  const float* enW2 = (const float*)d_in[5];  const float* enb2 = (const float*)d_in[6];
  const float* enW3 = (const float*)d_in[7];  const float* enb3 = (const float*)d_in[8];
  const float* enlg = (const float*)d_in[9];  const float* enlb = (const float*)d_in[10];

  const float* eeW1 = (const float*)d_in[11]; const float* eeb1 = (const float*)d_in[12];
  const float* eeW2 = (const float*)d_in[13]; const float* eeb2 = (const float*)d_in[14];
  const float* eeW3 = (const float*)d_in[15]; const float* eeb3 = (const float*)d_in[16];
  const float* eelg = (const float*)d_in[17]; const float* eelb = (const float*)d_in[18];

  const float* procW = (const float*)d_in[19];
  const float* procB = (const float*)d_in[20];
  const float* bnG   = (const float*)d_in[21];
  const float* bnB   = (const float*)d_in[22];

  const float* dW1 = (const float*)d_in[23]; const float* db1 = (const float*)d_in[24];
  const float* dW2 = (const float*)d_in[25]; const float* db2 = (const float*)d_in[26];
  const float* dW3 = (const float*)d_in[27]; const float* db3 = (const float*)d_in[28];
  const float* dlg = (const float*)d_in[29]; const float* dlb = (const float*)d_in[30];

  char* ws = (char*)d_ws;
  size_t off = 0;
  auto alloc = [&](size_t bytes) -> void* {
    void* p = ws + off;
    off = (off + bytes + 255) & ~(size_t)255;
    return p;
  };
  float* hn     = (float*)alloc((size_t)NN*DD*4);  // node state
  float* hbuf   = (float*)alloc((size_t)NN*DD*4);  // nodesum, then conv h
  float* ybuf   = (float*)alloc((size_t)NN*DD*4);  // BN input y
  float* dis    = (float*)alloc(NN*4);
  float* selfco = (float*)alloc(NN*4);
  float* invcnt = (float*)alloc(NN*4);
  float* Wf     = (float*)alloc(DD*DD*4);
  float* cvec   = (float*)alloc(DD*4);
  float* bnsums = (float*)alloc(2*DD*4);
  int* deg    = (int*)alloc(NN*4);
  int* cnt    = (int*)alloc(NN*4);
  int* rowptr = (int*)alloc((NN+1)*4);
  int* nextp  = (int*)alloc(NN*4);
  int* csr    = (int*)alloc((size_t)NE*4);

  hipMemsetAsync(deg, 0, NN*4, stream);
  hipMemsetAsync(cnt, 0, NN*4, stream);
  hipMemsetAsync(hbuf, 0, (size_t)NN*DD*4, stream);   // nodesum accumulator

  count_kernel<<<(NE+255)/256, 256, 0, stream>>>(src, dst, cnt, deg);
  nodeparams_kernel<<<(NN+255)/256, 256, 0, stream>>>(deg, cnt, dis, selfco, invcnt);
  scan_kernel<<<1, 256, 0, stream>>>(deg, rowptr, nextp);
  fill_kernel<<<(NE+255)/256, 256, 0, stream>>>(src, dst, nextp, csr);

  // encoders
  mlp_ln_kernel<19, false><<<NN/16, 128, 0, stream>>>(node_feat, NN,
      enW1, enb1, enW2, enb2, enW3, enb3, enlg, enlb, hn, nullptr);
  mlp_ln_kernel<4, true><<<NE/16, 128, 0, stream>>>(edge_feat, NE,
      eeW1, eeb1, eeW2, eeb2, eeW3, eeb3, eelg, eelb, hbuf, src);
  addmean_kernel<<<(NN*DD+255)/256, 256, 0, stream>>>(hn, hbuf, invcnt);

  // processor: 5 residual (conv -> leaky -> BN -> conv) steps
  for (int s = 0; s < 5; s++) {
    const float* W0  = procW + (size_t)(s*2+0)*DD*DD;
    const float* W1p = procW + (size_t)(s*2+1)*DD*DD;
    const float* b0  = procB + (size_t)(s*2+0)*DD;
    const float* b1p = procB + (size_t)(s*2+1)*DD;

    gemm128_kernel<<<NN/16 + 1, 128, 0, stream>>>(hn, W0, nullptr, hbuf, NN);
    gcn_agg_kernel<<<(NN+3)/4, 256, 0, stream>>>(hbuf, rowptr, csr, dis, selfco,
                                                 b0, nullptr, ybuf, 0);
    hipMemsetAsync(bnsums, 0, 2*DD*4, stream);
    bn_stats_kernel<<<512, 256, 0, stream>>>(ybuf, bnsums);
    bn_fold_kernel<<<1, 128, 0, stream>>>(bnsums, bnG + s*DD, bnB + s*DD, W1p, Wf, cvec);
    gemm128_kernel<<<NN/16 + 1, 128, 0, stream>>>(ybuf, Wf, cvec, hbuf, NN);
    gcn_agg_kernel<<<(NN+3)/4, 256, 0, stream>>>(hbuf, rowptr, csr, dis, selfco,
                                                 b1p, hn, hn, 1);
  }

  // decoder -> d_out (fp32)
  mlp_ln_kernel<128, false><<<NN/16 + 1, 128, 0, stream>>>(hn, NN,
      dW1, db1, dW2, db2, dW3, db3, dlg, dlb, (float*)d_out, nullptr);
}

// Round 4
// 2251.236 us; speedup vs baseline: 1.4786x; 1.4786x over previous
//
#include <hip/hip_runtime.h>

#define NN 50000
#define NE 800000
#define DD 128
#define LN_EPS 1e-5f

typedef __attribute__((ext_vector_type(8))) short v8s;    // 8 bf16
typedef __attribute__((ext_vector_type(4))) float f32x4;  // MFMA acc

__device__ __forceinline__ float leakyf(float x){ return x > 0.f ? x : 0.05f*x; }
__device__ __forceinline__ short f2bf(float f){
  unsigned u = __float_as_uint(f);
  u = (u + 0x7fffu + ((u >> 16) & 1u)) >> 16;   // RNE
  return (short)u;
}
__device__ __forceinline__ float bf2f(short h){
  return __uint_as_float(((unsigned)(unsigned short)h) << 16);
}
// split fp32 -> {hi, lo} bf16 (v ~ hi + lo, residual ~2^-17 relative)
__device__ __forceinline__ short2 f2bf2v(float v){
  short hi = f2bf(v);
  short lo = f2bf(v - bf2f(hi));
  return make_short2(hi, lo);
}

// ---------------------------------------------------------------------------
// Pack fp32 W[K][128] -> two bf16 planes Wh/Wl, layout [(k>>3)*128 + n][k&7]
// so a B-fragment for mfma_16x16x32_bf16 is one contiguous 16B load.
// ---------------------------------------------------------------------------
__global__ void pack_w_kernel(const float* __restrict__ W, short* __restrict__ Wh,
                              short* __restrict__ Wl, int K, int Kp)
{
  int idx = blockIdx.x*256 + threadIdx.x;
  if (idx >= Kp*128) return;
  int k = idx >> 7, n = idx & 127;
  float v = (k < K) ? W[k*128 + n] : 0.f;
  short2 t = f2bf2v(v);
  size_t o = ((size_t)(k >> 3)*128 + n)*8 + (k & 7);
  Wh[o] = t.x; Wl[o] = t.y;
}

#define MFMA3(ah, al, bh, bl, ac) \
  ac = __builtin_amdgcn_mfma_f32_16x16x32_bf16(al, bh, ac, 0,0,0); \
  ac = __builtin_amdgcn_mfma_f32_16x16x32_bf16(ah, bl, ac, 0,0,0); \
  ac = __builtin_amdgcn_mfma_f32_16x16x32_bf16(ah, bh, ac, 0,0,0);

// split a float4 pair into hi/lo v8s fragments
#define SPLIT8(f0, f1, h, l) { \
  short2 t0 = f2bf2v(f0.x), t1 = f2bf2v(f0.y), t2 = f2bf2v(f0.z), t3 = f2bf2v(f0.w); \
  short2 t4 = f2bf2v(f1.x), t5 = f2bf2v(f1.y), t6 = f2bf2v(f1.z), t7 = f2bf2v(f1.w); \
  h[0]=t0.x; l[0]=t0.y; h[1]=t1.x; l[1]=t1.y; h[2]=t2.x; l[2]=t2.y; h[3]=t3.x; l[3]=t3.y; \
  h[4]=t4.x; l[4]=t4.y; h[5]=t5.x; l[5]=t5.y; h[6]=t6.x; l[6]=t6.y; h[7]=t7.x; l[7]=t7.y; }

// ---------------------------------------------------------------------------
// 3-layer MLP + LayerNorm, split-bf16 3-MFMA (fp32-grade accuracy).
// Block=256 (4 waves, 2x2 over a 128x128 tile). Hidden acts live in LDS as
// hi/lo bf16 planes. LN fused in-register.
// ---------------------------------------------------------------------------
template<int IN_W, bool SCATTER>
__global__ __launch_bounds__(256)
void mlp_mfma_kernel(const float* __restrict__ x, int nrows,
                     const short* __restrict__ W1h, const short* __restrict__ W1l,
                     const float* __restrict__ b1,
                     const short* __restrict__ W2h, const short* __restrict__ W2l,
                     const float* __restrict__ b2,
                     const short* __restrict__ W3h, const short* __restrict__ W3l,
                     const float* __restrict__ b3,
                     const float* __restrict__ g, const float* __restrict__ bb,
                     float* __restrict__ out, const int* __restrict__ sidx)
{
  constexpr int L1K = (IN_W + 31) / 32;  // k-steps in layer 1
  __shared__ short Hh[128*136];          // hidden acts hi plane (+8 pad)
  __shared__ short Hl[128*136];          // hidden acts lo plane
  __shared__ float lnS[128][2], lnQ[128][2];
  __shared__ int sidx_s[128];

  const int tid  = threadIdx.x;
  const int lane = tid & 63, wave = tid >> 6;
  const int wr = wave >> 1, wc = wave & 1;
  const int quad = lane >> 4, low = lane & 15;
  const int row0 = blockIdx.x * 128;

  if (SCATTER && tid < 128) sidx_s[tid] = sidx[row0 + tid];  // NE % 128 == 0

  f32x4 acc[4][4];

  // ---------------- layer 1 (global A-frags) ----------------
  #pragma unroll
  for (int tm=0;tm<4;tm++)
    #pragma unroll
    for (int tn=0;tn<4;tn++) acc[tm][tn] = (f32x4)0.f;

  for (int ks = 0; ks < L1K; ks++) {
    v8s ah[4], al[4], bh[4], bl[4];
    #pragma unroll
    for (int tm=0;tm<4;tm++) {
      int r = row0 + wr*64 + tm*16 + low;
      v8s h = (v8s)0, l = (v8s)0;
      if (IN_W % 32 == 0) {
        if (r < nrows) {
          const float* p = x + (size_t)r*IN_W + ks*32 + quad*8;
          float4 f0 = *(const float4*)p;
          float4 f1 = *(const float4*)(p + 4);
          SPLIT8(f0, f1, h, l);
        }
      } else {
        #pragma unroll
        for (int j=0;j<8;j++) {
          int k = ks*32 + quad*8 + j;
          if (k < IN_W && r < nrows) {
            short2 t = f2bf2v(x[(size_t)r*IN_W + k]);
            h[j] = t.x; l[j] = t.y;
          }
        }
      }
      ah[tm] = h; al[tm] = l;
    }
    #pragma unroll
    for (int tn=0;tn<4;tn++) {
      size_t o = ((size_t)(ks*4+quad)*128 + wc*64 + tn*16 + low)*8;
      bh[tn] = *(const v8s*)(W1h + o);
      bl[tn] = *(const v8s*)(W1l + o);
    }
    #pragma unroll
    for (int tm=0;tm<4;tm++)
      #pragma unroll
      for (int tn=0;tn<4;tn++) { MFMA3(ah[tm], al[tm], bh[tn], bl[tn], acc[tm][tn]); }
  }
  #pragma unroll
  for (int tn=0;tn<4;tn++) {
    float bv = b1[wc*64 + tn*16 + low];
    #pragma unroll
    for (int tm=0;tm<4;tm++)
      #pragma unroll
      for (int i=0;i<4;i++) {
        int idx = (wr*64+tm*16+quad*4+i)*136 + wc*64+tn*16+low;
        short2 t = f2bf2v(leakyf(acc[tm][tn][i] + bv));
        Hh[idx] = t.x; Hl[idx] = t.y;
      }
  }
  __syncthreads();

  // ---------------- layer 2 (LDS A-frags) ----------------
  #pragma unroll
  for (int tm=0;tm<4;tm++)
    #pragma unroll
    for (int tn=0;tn<4;tn++) acc[tm][tn] = (f32x4)0.f;
  #pragma unroll
  for (int ks=0;ks<4;ks++) {
    v8s ah[4], al[4], bh[4], bl[4];
    #pragma unroll
    for (int tm=0;tm<4;tm++) {
      int idx = (wr*64+tm*16+low)*136 + ks*32 + quad*8;
      ah[tm] = *(const v8s*)&Hh[idx];
      al[tm] = *(const v8s*)&Hl[idx];
    }
    #pragma unroll
    for (int tn=0;tn<4;tn++) {
      size_t o = ((size_t)(ks*4+quad)*128 + wc*64 + tn*16 + low)*8;
      bh[tn] = *(const v8s*)(W2h + o);
      bl[tn] = *(const v8s*)(W2l + o);
    }
    #pragma unroll
    for (int tm=0;tm<4;tm++)
      #pragma unroll
      for (int tn=0;tn<4;tn++) { MFMA3(ah[tm], al[tm], bh[tn], bl[tn], acc[tm][tn]); }
  }
  __syncthreads();   // all H reads done before overwrite
  #pragma unroll
  for (int tn=0;tn<4;tn++) {
    float bv = b2[wc*64 + tn*16 + low];
    #pragma unroll
    for (int tm=0;tm<4;tm++)
      #pragma unroll
      for (int i=0;i<4;i++) {
        int idx = (wr*64+tm*16+quad*4+i)*136 + wc*64+tn*16+low;
        short2 t = f2bf2v(leakyf(acc[tm][tn][i] + bv));
        Hh[idx] = t.x; Hl[idx] = t.y;
      }
  }
  __syncthreads();

  // ---------------- layer 3 ----------------
  #pragma unroll
  for (int tm=0;tm<4;tm++)
    #pragma unroll
    for (int tn=0;tn<4;tn++) acc[tm][tn] = (f32x4)0.f;
  #pragma unroll
  for (int ks=0;ks<4;ks++) {
    v8s ah[4], al[4], bh[4], bl[4];
    #pragma unroll
    for (int tm=0;tm<4;tm++) {
      int idx = (wr*64+tm*16+low)*136 + ks*32 + quad*8;
      ah[tm] = *(const v8s*)&Hh[idx];
      al[tm] = *(const v8s*)&Hl[idx];
    }
    #pragma unroll
    for (int tn=0;tn<4;tn++) {
      size_t o = ((size_t)(ks*4+quad)*128 + wc*64 + tn*16 + low)*8;
      bh[tn] = *(const v8s*)(W3h + o);
      bl[tn] = *(const v8s*)(W3l + o);
    }
    #pragma unroll
    for (int tm=0;tm<4;tm++)
      #pragma unroll
      for (int tn=0;tn<4;tn++) { MFMA3(ah[tm], al[tm], bh[tn], bl[tn], acc[tm][tn]); }
  }
  // + b3
  #pragma unroll
  for (int tn=0;tn<4;tn++) {
    float bv = b3[wc*64 + tn*16 + low];
    #pragma unroll
    for (int tm=0;tm<4;tm++)
      #pragma unroll
      for (int i=0;i<4;i++) acc[tm][tn][i] += bv;
  }

  // ---------------- fused LayerNorm ----------------
  #pragma unroll
  for (int tm=0;tm<4;tm++)
    #pragma unroll
    for (int i=0;i<4;i++) {
      float s = acc[tm][0][i] + acc[tm][1][i] + acc[tm][2][i] + acc[tm][3][i];
      float q = acc[tm][0][i]*acc[tm][0][i] + acc[tm][1][i]*acc[tm][1][i]
              + acc[tm][2][i]*acc[tm][2][i] + acc[tm][3][i]*acc[tm][3][i];
      s += __shfl_xor(s, 1); q += __shfl_xor(q, 1);
      s += __shfl_xor(s, 2); q += __shfl_xor(q, 2);
      s += __shfl_xor(s, 4); q += __shfl_xor(q, 4);
      s += __shfl_xor(s, 8); q += __shfl_xor(q, 8);
      if (low == tm*4 + i) {
        int r = wr*64 + tm*16 + quad*4 + i;
        lnS[r][wc] = s; lnQ[r][wc] = q;
      }
    }
  __syncthreads();

  float g4[4], bb4[4];
  #pragma unroll
  for (int tn=0;tn<4;tn++) { int c = wc*64+tn*16+low; g4[tn] = g[c]; bb4[tn] = bb[c]; }

  #pragma unroll
  for (int tm=0;tm<4;tm++)
    #pragma unroll
    for (int i=0;i<4;i++) {
      int r = wr*64 + tm*16 + quad*4 + i;
      float s = lnS[r][0] + lnS[r][1];
      float q = lnQ[r][0] + lnQ[r][1];
      float m = s * (1.f/128.f);
      float var = q * (1.f/128.f) - m*m;
      float rs = rsqrtf(var + LN_EPS);
      int gr = row0 + r;
      if (!SCATTER && gr >= nrows) continue;
      #pragma unroll
      for (int tn=0;tn<4;tn++) {
        float v = (acc[tm][tn][i] - m) * rs * g4[tn] + bb4[tn];
        int c = wc*64 + tn*16 + low;
        if (SCATTER) atomicAdd(&out[(size_t)sidx_s[r]*DD + c], v);
        else         out[(size_t)gr*DD + c] = v;
      }
    }
}

// ---------------------------------------------------------------------------
// out = x @ W (+ initv), split-bf16 3-MFMA, no LDS (A split in-register from
// global fp32, B hi/lo packed & L2-resident).
// ---------------------------------------------------------------------------
__global__ __launch_bounds__(256)
void gemm_mfma_kernel(const float* __restrict__ x,
                      const short* __restrict__ Wh, const short* __restrict__ Wl,
                      const float* __restrict__ initv, float* __restrict__ out, int nrows)
{
  const int tid  = threadIdx.x;
  const int lane = tid & 63, wave = tid >> 6;
  const int wr = wave >> 1, wc = wave & 1;
  const int quad = lane >> 4, low = lane & 15;
  const int row0 = blockIdx.x * 128;

  f32x4 acc[4][4];
  #pragma unroll
  for (int tm=0;tm<4;tm++)
    #pragma unroll
    for (int tn=0;tn<4;tn++) acc[tm][tn] = (f32x4)0.f;

  #pragma unroll
  for (int ks=0;ks<4;ks++) {
    v8s ah[4], al[4], bh[4], bl[4];
    #pragma unroll
    for (int tm=0;tm<4;tm++) {
      int r = row0 + wr*64 + tm*16 + low;
      v8s h = (v8s)0, l = (v8s)0;
      if (r < nrows) {
        const float* p = x + (size_t)r*DD + ks*32 + quad*8;
        float4 f0 = *(const float4*)p;
        float4 f1 = *(const float4*)(p + 4);
        SPLIT8(f0, f1, h, l);
      }
      ah[tm] = h; al[tm] = l;
    }
    #pragma unroll
    for (int tn=0;tn<4;tn++) {
      size_t o = ((size_t)(ks*4+quad)*128 + wc*64 + tn*16 + low)*8;
      bh[tn] = *(const v8s*)(Wh + o);
      bl[tn] = *(const v8s*)(Wl + o);
    }
    #pragma unroll
    for (int tm=0;tm<4;tm++)
      #pragma unroll
      for (int tn=0;tn<4;tn++) { MFMA3(ah[tm], al[tm], bh[tn], bl[tn], acc[tm][tn]); }
  }

  #pragma unroll
  for (int tn=0;tn<4;tn++) {
    int c = wc*64 + tn*16 + low;
    float iv = initv ? initv[c] : 0.f;
    #pragma unroll
    for (int tm=0;tm<4;tm++)
      #pragma unroll
      for (int i=0;i<4;i++) {
        int gr = row0 + wr*64 + tm*16 + quad*4 + i;
        if (gr < nrows) out[(size_t)gr*DD + c] = acc[tm][tn][i] + iv;
      }
  }
}

// ---------------------------------------------------------------------------
// GCN aggregation via dst-CSR (fp32).
// ---------------------------------------------------------------------------
__global__ __launch_bounds__(256)
void gcn_agg_kernel(const float* __restrict__ h, const int* __restrict__ rowptr,
                    const int* __restrict__ csr_src, const float* __restrict__ dis,
                    const float* __restrict__ selfco, const float* __restrict__ bias,
                    const float* __restrict__ resid, float* __restrict__ out, int mode)
{
  const int wv = threadIdx.x >> 6, lane = threadIdx.x & 63;
  const int i = blockIdx.x*4 + wv;
  if (i >= NN) return;
  const float2* h2 = (const float2*)h;
  const float di = dis[i];
  const float sc = selfco[i];
  float2 hv = h2[(size_t)i*64 + lane];
  float ax = sc*hv.x, ay = sc*hv.y;
  const int beg = rowptr[i], end = rowptr[i+1];
  for (int j = beg; j < end; j++) {
    int s = csr_src[j];
    float c = dis[s] * di;
    float2 v = h2[(size_t)s*64 + lane];
    ax += c*v.x; ay += c*v.y;
  }
  ax += bias[2*lane]; ay += bias[2*lane+1];
  size_t o = (size_t)i*64 + lane;
  float2 r;
  if (mode == 0) { r.x = leakyf(ax); r.y = leakyf(ay); }
  else { float2 rs = ((const float2*)resid)[o]; r.x = rs.x + ax; r.y = rs.y + ay; }
  ((float2*)out)[o] = r;
}

// ---------------------------------------------------------------------------
// Graph setup
// ---------------------------------------------------------------------------
__global__ void count_kernel(const int* __restrict__ src, const int* __restrict__ dst,
                             int* __restrict__ cnt_src, int* __restrict__ deg_dst)
{
  int e = blockIdx.x*blockDim.x + threadIdx.x;
  if (e < NE) {
    atomicAdd(&cnt_src[src[e]], 1);
    atomicAdd(&deg_dst[dst[e]], 1);
  }
}

__global__ void nodeparams_kernel(const int* __restrict__ deg_dst, const int* __restrict__ cnt_src,
                                  float* __restrict__ dis, float* __restrict__ selfco,
                                  float* __restrict__ invcnt)
{
  int i = blockIdx.x*blockDim.x + threadIdx.x;
  if (i < NN) {
    float d = (float)deg_dst[i] + 1.0f;
    dis[i] = rsqrtf(d);
    selfco[i] = 1.0f / d;
    invcnt[i] = 1.0f / fmaxf((float)cnt_src[i], 1.0f);
  }
}

__global__ void scan_kernel(const int* __restrict__ deg, int* __restrict__ rowptr,
                            int* __restrict__ nextp)
{
  const int T = 256;
  int tid = threadIdx.x;
  int chunk = (NN + T - 1) / T;
  int begin = tid*chunk, end = begin + chunk; if (end > NN) end = NN; if (begin > NN) begin = NN;
  int s = 0;
  for (int i = begin; i < end; i++) s += deg[i];
  __shared__ int ps[T];
  ps[tid] = s; __syncthreads();
  for (int off = 1; off < T; off <<= 1) {
    int v = 0;
    if (tid >= off) v = ps[tid - off];
    __syncthreads();
    if (tid >= off) ps[tid] += v;
    __syncthreads();
  }
  int base = (tid == 0) ? 0 : ps[tid-1];
  for (int i = begin; i < end; i++) { rowptr[i] = base; nextp[i] = base; base += deg[i]; }
  if (tid == T-1) rowptr[NN] = base;
}

__global__ void fill_kernel(const int* __restrict__ src, const int* __restrict__ dst,
                            int* __restrict__ nextp, int* __restrict__ csr_src)
{
  int e = blockIdx.x*blockDim.x + threadIdx.x;
  if (e < NE) {
    int pos = atomicAdd(&nextp[dst[e]], 1);
    csr_src[pos] = src[e];
  }
}

__global__ void addmean_kernel(float* __restrict__ hn, const float* __restrict__ nodesum,
                               const float* __restrict__ invcnt)
{
  int t = blockIdx.x*blockDim.x + threadIdx.x;
  if (t < NN*DD) hn[t] += nodesum[t] * invcnt[t >> 7];
}

// ---------------------------------------------------------------------------
// BatchNorm stats + fold into packed hi/lo bf16 conv2 weight
// ---------------------------------------------------------------------------
__global__ __launch_bounds__(256)
void bn_stats_kernel(const float* __restrict__ y, float* __restrict__ sums)
{
  int col = threadIdx.x & 127, grp = threadIdx.x >> 7;
  float s = 0.f, ss = 0.f;
  for (int i = blockIdx.x*2 + grp; i < NN; i += gridDim.x*2) {
    float v = y[(size_t)i*DD + col];
    s += v; ss += v*v;
  }
  __shared__ float ls[256], lss[256];
  ls[threadIdx.x] = s; lss[threadIdx.x] = ss;
  __syncthreads();
  if (grp == 0) {
    atomicAdd(&sums[col],      ls[col]  + ls[col+128]);
    atomicAdd(&sums[DD + col], lss[col] + lss[col+128]);
  }
}

__global__ void bn_fold_kernel(const float* __restrict__ sums, const float* __restrict__ g,
                               const float* __restrict__ b, const float* __restrict__ W2,
                               short* __restrict__ Wfh, short* __restrict__ Wfl,
                               float* __restrict__ cvec)
{
  int col = threadIdx.x;  // 128 threads
  __shared__ float scale[DD], shift[DD];
  float m = sums[col] / (float)NN;
  float var = sums[DD + col] / (float)NN - m*m;
  float is = rsqrtf(var + LN_EPS);
  float sc = is * g[col];
  scale[col] = sc;
  shift[col] = b[col] - m * sc;
  __syncthreads();
  float c = 0.f;
  for (int k = 0; k < DD; k++) {
    float w = W2[k*DD + col];
    float ws = w * scale[k];
    short2 t = f2bf2v(ws);
    size_t o = ((size_t)(k >> 3)*128 + col)*8 + (k & 7);
    Wfh[o] = t.x; Wfl[o] = t.y;
    c += shift[k] * w;
  }
  cvec[col] = c;
}

// ---------------------------------------------------------------------------
extern "C" void kernel_launch(void* const* d_in, const int* in_sizes, int n_in,
                              void* d_out, int out_size, void* d_ws, size_t ws_size,
                              hipStream_t stream)
{
  const float* node_feat = (const float*)d_in[0];
  const float* edge_feat = (const float*)d_in[1];
  const int*   edge_index = (const int*)d_in[2];
  const int* src = edge_index;
  const int* dst = edge_index + NE;

  const float* enW1 = (const float*)d_in[3];  const float* enb1 = (const float*)d_in[4];
  const float* enW2 = (const float*)d_in[5];  const float* enb2 = (const float*)d_in[6];
  const float* enW3 = (const float*)d_in[7];  const float* enb3 = (const float*)d_in[8];
  const float* enlg = (const float*)d_in[9];  const float* enlb = (const float*)d_in[10];

  const float* eeW1 = (const float*)d_in[11]; const float* eeb1 = (const float*)d_in[12];
  const float* eeW2 = (const float*)d_in[13]; const float* eeb2 = (const float*)d_in[14];
  const float* eeW3 = (const float*)d_in[15]; const float* eeb3 = (const float*)d_in[16];
  const float* eelg = (const float*)d_in[17]; const float* eelb = (const float*)d_in[18];

  const float* procW = (const float*)d_in[19];
  const float* procB = (const float*)d_in[20];
  const float* bnG   = (const float*)d_in[21];
  const float* bnB   = (const float*)d_in[22];

  const float* dW1 = (const float*)d_in[23]; const float* db1 = (const float*)d_in[24];
  const float* dW2 = (const float*)d_in[25]; const float* db2 = (const float*)d_in[26];
  const float* dW3 = (const float*)d_in[27]; const float* db3 = (const float*)d_in[28];
  const float* dlg = (const float*)d_in[29]; const float* dlb = (const float*)d_in[30];

  char* ws = (char*)d_ws;
  size_t off = 0;
  auto alloc = [&](size_t bytes) -> void* {
    void* p = ws + off;
    off = (off + bytes + 255) & ~(size_t)255;
    return p;
  };
  float* hn     = (float*)alloc((size_t)NN*DD*4);
  float* hbuf   = (float*)alloc((size_t)NN*DD*4);
  float* ybuf   = (float*)alloc((size_t)NN*DD*4);
  float* dis    = (float*)alloc(NN*4);
  float* selfco = (float*)alloc(NN*4);
  float* invcnt = (float*)alloc(NN*4);
  float* cvec   = (float*)alloc(DD*4);
  float* bnsums = (float*)alloc(2*DD*4);
  int* deg    = (int*)alloc(NN*4);
  int* cnt    = (int*)alloc(NN*4);
  int* rowptr = (int*)alloc((NN+1)*4);
  int* nextp  = (int*)alloc(NN*4);
  int* csr    = (int*)alloc((size_t)NE*4);
  // packed bf16 hi/lo weight planes
  auto allocW = [&](int kp) { return (short*)alloc((size_t)kp*128*2); };
  short *pN1h=allocW(32),  *pN1l=allocW(32);
  short *pN2h=allocW(128), *pN2l=allocW(128);
  short *pN3h=allocW(128), *pN3l=allocW(128);
  short *pE1h=allocW(32),  *pE1l=allocW(32);
  short *pE2h=allocW(128), *pE2l=allocW(128);
  short *pE3h=allocW(128), *pE3l=allocW(128);
  short *pD1h=allocW(128), *pD1l=allocW(128);
  short *pD2h=allocW(128), *pD2l=allocW(128);
  short *pD3h=allocW(128), *pD3l=allocW(128);
  short *pP0h[5], *pP0l[5];
  for (int s = 0; s < 5; s++) { pP0h[s]=allocW(128); pP0l[s]=allocW(128); }
  short *pWfh=allocW(128), *pWfl=allocW(128);

  (void)hipMemsetAsync(deg, 0, NN*4, stream);
  (void)hipMemsetAsync(cnt, 0, NN*4, stream);
  (void)hipMemsetAsync(hbuf, 0, (size_t)NN*DD*4, stream);   // edge scatter-sum accumulator

  // pack static weights to bf16 hi/lo
  const int G32 = (32*128+255)/256, G128 = (128*128+255)/256;
  pack_w_kernel<<<G32, 256, 0, stream>>>(enW1, pN1h, pN1l, 19, 32);
  pack_w_kernel<<<G128,256, 0, stream>>>(enW2, pN2h, pN2l, 128, 128);
  pack_w_kernel<<<G128,256, 0, stream>>>(enW3, pN3h, pN3l, 128, 128);
  pack_w_kernel<<<G32, 256, 0, stream>>>(eeW1, pE1h, pE1l, 4, 32);
  pack_w_kernel<<<G128,256, 0, stream>>>(eeW2, pE2h, pE2l, 128, 128);
  pack_w_kernel<<<G128,256, 0, stream>>>(eeW3, pE3h, pE3l, 128, 128);
  pack_w_kernel<<<G128,256, 0, stream>>>(dW1, pD1h, pD1l, 128, 128);
  pack_w_kernel<<<G128,256, 0, stream>>>(dW2, pD2h, pD2l, 128, 128);
  pack_w_kernel<<<G128,256, 0, stream>>>(dW3, pD3h, pD3l, 128, 128);
  for (int s = 0; s < 5; s++)
    pack_w_kernel<<<G128,256,0,stream>>>(procW + (size_t)(s*2)*DD*DD, pP0h[s], pP0l[s], 128, 128);

  // graph setup
  count_kernel<<<(NE+255)/256, 256, 0, stream>>>(src, dst, cnt, deg);
  nodeparams_kernel<<<(NN+255)/256, 256, 0, stream>>>(deg, cnt, dis, selfco, invcnt);
  scan_kernel<<<1, 256, 0, stream>>>(deg, rowptr, nextp);
  fill_kernel<<<(NE+255)/256, 256, 0, stream>>>(src, dst, nextp, csr);

  const int GN = (NN + 127) / 128;   // 391
  const int GE = NE / 128;           // 6250

  // encoders
  mlp_mfma_kernel<19, false><<<GN, 256, 0, stream>>>(node_feat, NN,
      pN1h, pN1l, enb1, pN2h, pN2l, enb2, pN3h, pN3l, enb3, enlg, enlb, hn, nullptr);
  mlp_mfma_kernel<4, true><<<GE, 256, 0, stream>>>(edge_feat, NE,
      pE1h, pE1l, eeb1, pE2h, pE2l, eeb2, pE3h, pE3l, eeb3, eelg, eelb, hbuf, src);
  addmean_kernel<<<(NN*DD+255)/256, 256, 0, stream>>>(hn, hbuf, invcnt);

  // processor: 5 residual (conv -> leaky -> BN -> conv) steps, BN folded into W2
  for (int s = 0; s < 5; s++) {
    const float* Wc2 = procW + (size_t)(s*2+1)*DD*DD;
    const float* b0  = procB + (size_t)(s*2+0)*DD;
    const float* b1p = procB + (size_t)(s*2+1)*DD;

    gemm_mfma_kernel<<<GN, 256, 0, stream>>>(hn, pP0h[s], pP0l[s], nullptr, hbuf, NN);
    gcn_agg_kernel<<<(NN+3)/4, 256, 0, stream>>>(hbuf, rowptr, csr, dis, selfco,
                                                 b0, nullptr, ybuf, 0);
    (void)hipMemsetAsync(bnsums, 0, 2*DD*4, stream);
    bn_stats_kernel<<<512, 256, 0, stream>>>(ybuf, bnsums);
    bn_fold_kernel<<<1, 128, 0, stream>>>(bnsums, bnG + s*DD, bnB + s*DD, Wc2, pWfh, pWfl, cvec);
    gemm_mfma_kernel<<<GN, 256, 0, stream>>>(ybuf, pWfh, pWfl, cvec, hbuf, NN);
    gcn_agg_kernel<<<(NN+3)/4, 256, 0, stream>>>(hbuf, rowptr, csr, dis, selfco,
                                                 b1p, hn, hn, 1);
  }

  // decoder -> d_out (fp32)
  mlp_mfma_kernel<128, false><<<GN, 256, 0, stream>>>(hn, NN,
      pD1h, pD1l, db1, pD2h, pD2l, db2, pD3h, pD3l, db3, dlg, dlb, (float*)d_out, nullptr);
}

// Round 5
// 1905.801 us; speedup vs baseline: 1.7466x; 1.1813x over previous
//
#include <hip/hip_runtime.h>

#define NN 50000
#define NE 800000
#define DD 128
#define LN_EPS 1e-5f

typedef __attribute__((ext_vector_type(8))) short v8s;    // 8 bf16
typedef __attribute__((ext_vector_type(4))) float f32x4;  // MFMA acc

__device__ __forceinline__ float leakyf(float x){ return x > 0.f ? x : 0.05f*x; }
__device__ __forceinline__ short f2bf(float f){
  unsigned u = __float_as_uint(f);
  u = (u + 0x7fffu + ((u >> 16) & 1u)) >> 16;   // RNE
  return (short)u;
}
__device__ __forceinline__ float bf2f(short h){
  return __uint_as_float(((unsigned)(unsigned short)h) << 16);
}
// split fp32 -> {hi, lo}: hi = truncated top-16 (cheap), lo = RNE(residual).
// v ~ hi + lo with residual ~2^-17 relative.
__device__ __forceinline__ short2 f2bf2v(float v){
  unsigned u = __float_as_uint(v);
  short hi = (short)(u >> 16);
  float lo = v - __uint_as_float(u & 0xffff0000u);
  return make_short2(hi, f2bf(lo));
}

// ---------------------------------------------------------------------------
// Pack fp32 W[K][128] -> two bf16 planes Wh/Wl, layout [(k>>3)*128 + n][k&7]
// ---------------------------------------------------------------------------
__global__ void pack_w_kernel(const float* __restrict__ W, short* __restrict__ Wh,
                              short* __restrict__ Wl, int K, int Kp)
{
  int idx = blockIdx.x*256 + threadIdx.x;
  if (idx >= Kp*128) return;
  int k = idx >> 7, n = idx & 127;
  float v = (k < K) ? W[k*128 + n] : 0.f;
  short2 t = f2bf2v(v);
  size_t o = ((size_t)(k >> 3)*128 + n)*8 + (k & 7);
  Wh[o] = t.x; Wl[o] = t.y;
}

#define MFMA3(ah, al, bh, bl, ac) \
  ac = __builtin_amdgcn_mfma_f32_16x16x32_bf16(al, bh, ac, 0,0,0); \
  ac = __builtin_amdgcn_mfma_f32_16x16x32_bf16(ah, bl, ac, 0,0,0); \
  ac = __builtin_amdgcn_mfma_f32_16x16x32_bf16(ah, bh, ac, 0,0,0);

#define SPLIT8(f0, f1, h, l) { \
  short2 t0 = f2bf2v(f0.x), t1 = f2bf2v(f0.y), t2 = f2bf2v(f0.z), t3 = f2bf2v(f0.w); \
  short2 t4 = f2bf2v(f1.x), t5 = f2bf2v(f1.y), t6 = f2bf2v(f1.z), t7 = f2bf2v(f1.w); \
  h[0]=t0.x; l[0]=t0.y; h[1]=t1.x; l[1]=t1.y; h[2]=t2.x; l[2]=t2.y; h[3]=t3.x; l[3]=t3.y; \
  h[4]=t4.x; l[4]=t4.y; h[5]=t5.x; l[5]=t5.y; h[6]=t6.x; l[6]=t6.y; h[7]=t7.x; l[7]=t7.y; }

// ---------------------------------------------------------------------------
// 3-layer MLP + LayerNorm, split-bf16 3-MFMA.
// SCATTER (edge encoder): edges processed in src-sorted order via eperm,
// output seg-reduced per src in LDS, one atomicAdd per (segment, col).
// ---------------------------------------------------------------------------
template<int IN_W, bool SCATTER>
__global__ __launch_bounds__(256)
void mlp_mfma_kernel(const float* __restrict__ x, int nrows,
                     const short* __restrict__ W1h, const short* __restrict__ W1l,
                     const float* __restrict__ b1,
                     const short* __restrict__ W2h, const short* __restrict__ W2l,
                     const float* __restrict__ b2,
                     const short* __restrict__ W3h, const short* __restrict__ W3l,
                     const float* __restrict__ b3,
                     const float* __restrict__ g, const float* __restrict__ bb,
                     float* __restrict__ out,
                     const int* __restrict__ sidx,   // src-sorted src values
                     const int* __restrict__ eperm)  // sorted pos -> edge id
{
  constexpr int L1K = (IN_W + 31) / 32;
  __shared__ __align__(16) short Hboth[2*128*136];   // hi/lo act planes; reused as fp32 seg buffer
  short* Hh = Hboth;
  short* Hl = Hboth + 128*136;
  float* Hf = (float*)Hboth;                          // stride 132 in reduce phase
  __shared__ float lnS[128][2], lnQ[128][2];
  __shared__ int sidx_s[128];
  __shared__ int eperm_s[128];

  const int tid  = threadIdx.x;
  const int lane = tid & 63, wave = tid >> 6;
  const int wr = wave >> 1, wc = wave & 1;
  const int quad = lane >> 4, low = lane & 15;
  const int row0 = blockIdx.x * 128;

  if (SCATTER) {
    if (tid < 128) {
      sidx_s[tid]  = sidx[row0 + tid];   // NE % 128 == 0
      eperm_s[tid] = eperm[row0 + tid];
    }
    __syncthreads();
  }

  f32x4 acc[4][4];

  // ---------------- layer 1 ----------------
  #pragma unroll
  for (int tm=0;tm<4;tm++)
    #pragma unroll
    for (int tn=0;tn<4;tn++) acc[tm][tn] = (f32x4)0.f;

  for (int ks = 0; ks < L1K; ks++) {
    v8s ah[4], al[4], bh[4], bl[4];
    #pragma unroll
    for (int tm=0;tm<4;tm++) {
      int lr = wr*64 + tm*16 + low;
      v8s h = (v8s)0, l = (v8s)0;
      if (SCATTER && IN_W == 4) {
        if (quad == 0) {
          int e = eperm_s[lr];
          float4 f = ((const float4*)x)[e];
          short2 t0 = f2bf2v(f.x), t1 = f2bf2v(f.y), t2 = f2bf2v(f.z), t3 = f2bf2v(f.w);
          h[0]=t0.x; l[0]=t0.y; h[1]=t1.x; l[1]=t1.y;
          h[2]=t2.x; l[2]=t2.y; h[3]=t3.x; l[3]=t3.y;
        }
      } else if (IN_W % 32 == 0) {
        int r = row0 + lr;
        if (r < nrows) {
          const float* p = x + (size_t)r*IN_W + ks*32 + quad*8;
          float4 f0 = *(const float4*)p;
          float4 f1 = *(const float4*)(p + 4);
          SPLIT8(f0, f1, h, l);
        }
      } else {
        int r = row0 + lr;
        #pragma unroll
        for (int j=0;j<8;j++) {
          int k = ks*32 + quad*8 + j;
          if (k < IN_W && r < nrows) {
            short2 t = f2bf2v(x[(size_t)r*IN_W + k]);
            h[j] = t.x; l[j] = t.y;
          }
        }
      }
      ah[tm] = h; al[tm] = l;
    }
    #pragma unroll
    for (int tn=0;tn<4;tn++) {
      size_t o = ((size_t)(ks*4+quad)*128 + wc*64 + tn*16 + low)*8;
      bh[tn] = *(const v8s*)(W1h + o);
      bl[tn] = *(const v8s*)(W1l + o);
    }
    #pragma unroll
    for (int tm=0;tm<4;tm++)
      #pragma unroll
      for (int tn=0;tn<4;tn++) { MFMA3(ah[tm], al[tm], bh[tn], bl[tn], acc[tm][tn]); }
  }
  if (SCATTER) __syncthreads();   // eperm_s reads done (aliases nothing, but keep order sane)
  #pragma unroll
  for (int tn=0;tn<4;tn++) {
    float bv = b1[wc*64 + tn*16 + low];
    #pragma unroll
    for (int tm=0;tm<4;tm++)
      #pragma unroll
      for (int i=0;i<4;i++) {
        int idx = (wr*64+tm*16+quad*4+i)*136 + wc*64+tn*16+low;
        short2 t = f2bf2v(leakyf(acc[tm][tn][i] + bv));
        Hh[idx] = t.x; Hl[idx] = t.y;
      }
  }
  __syncthreads();

  // ---------------- layer 2 ----------------
  #pragma unroll
  for (int tm=0;tm<4;tm++)
    #pragma unroll
    for (int tn=0;tn<4;tn++) acc[tm][tn] = (f32x4)0.f;
  #pragma unroll
  for (int ks=0;ks<4;ks++) {
    v8s ah[4], al[4], bh[4], bl[4];
    #pragma unroll
    for (int tm=0;tm<4;tm++) {
      int idx = (wr*64+tm*16+low)*136 + ks*32 + quad*8;
      ah[tm] = *(const v8s*)&Hh[idx];
      al[tm] = *(const v8s*)&Hl[idx];
    }
    #pragma unroll
    for (int tn=0;tn<4;tn++) {
      size_t o = ((size_t)(ks*4+quad)*128 + wc*64 + tn*16 + low)*8;
      bh[tn] = *(const v8s*)(W2h + o);
      bl[tn] = *(const v8s*)(W2l + o);
    }
    #pragma unroll
    for (int tm=0;tm<4;tm++)
      #pragma unroll
      for (int tn=0;tn<4;tn++) { MFMA3(ah[tm], al[tm], bh[tn], bl[tn], acc[tm][tn]); }
  }
  __syncthreads();
  #pragma unroll
  for (int tn=0;tn<4;tn++) {
    float bv = b2[wc*64 + tn*16 + low];
    #pragma unroll
    for (int tm=0;tm<4;tm++)
      #pragma unroll
      for (int i=0;i<4;i++) {
        int idx = (wr*64+tm*16+quad*4+i)*136 + wc*64+tn*16+low;
        short2 t = f2bf2v(leakyf(acc[tm][tn][i] + bv));
        Hh[idx] = t.x; Hl[idx] = t.y;
      }
  }
  __syncthreads();

  // ---------------- layer 3 ----------------
  #pragma unroll
  for (int tm=0;tm<4;tm++)
    #pragma unroll
    for (int tn=0;tn<4;tn++) acc[tm][tn] = (f32x4)0.f;
  #pragma unroll
  for (int ks=0;ks<4;ks++) {
    v8s ah[4], al[4], bh[4], bl[4];
    #pragma unroll
    for (int tm=0;tm<4;tm++) {
      int idx = (wr*64+tm*16+low)*136 + ks*32 + quad*8;
      ah[tm] = *(const v8s*)&Hh[idx];
      al[tm] = *(const v8s*)&Hl[idx];
    }
    #pragma unroll
    for (int tn=0;tn<4;tn++) {
      size_t o = ((size_t)(ks*4+quad)*128 + wc*64 + tn*16 + low)*8;
      bh[tn] = *(const v8s*)(W3h + o);
      bl[tn] = *(const v8s*)(W3l + o);
    }
    #pragma unroll
    for (int tm=0;tm<4;tm++)
      #pragma unroll
      for (int tn=0;tn<4;tn++) { MFMA3(ah[tm], al[tm], bh[tn], bl[tn], acc[tm][tn]); }
  }
  #pragma unroll
  for (int tn=0;tn<4;tn++) {
    float bv = b3[wc*64 + tn*16 + low];
    #pragma unroll
    for (int tm=0;tm<4;tm++)
      #pragma unroll
      for (int i=0;i<4;i++) acc[tm][tn][i] += bv;
  }

  // ---------------- fused LayerNorm ----------------
  #pragma unroll
  for (int tm=0;tm<4;tm++)
    #pragma unroll
    for (int i=0;i<4;i++) {
      float s = acc[tm][0][i] + acc[tm][1][i] + acc[tm][2][i] + acc[tm][3][i];
      float q = acc[tm][0][i]*acc[tm][0][i] + acc[tm][1][i]*acc[tm][1][i]
              + acc[tm][2][i]*acc[tm][2][i] + acc[tm][3][i]*acc[tm][3][i];
      s += __shfl_xor(s, 1); q += __shfl_xor(q, 1);
      s += __shfl_xor(s, 2); q += __shfl_xor(q, 2);
      s += __shfl_xor(s, 4); q += __shfl_xor(q, 4);
      s += __shfl_xor(s, 8); q += __shfl_xor(q, 8);
      if (low == tm*4 + i) {
        int r = wr*64 + tm*16 + quad*4 + i;
        lnS[r][wc] = s; lnQ[r][wc] = q;
      }
    }
  __syncthreads();   // also guarantees all layer-3 H reads are done (Hf reuse below)

  float g4[4], bb4[4];
  #pragma unroll
  for (int tn=0;tn<4;tn++) { int c = wc*64+tn*16+low; g4[tn] = g[c]; bb4[tn] = bb[c]; }

  #pragma unroll
  for (int tm=0;tm<4;tm++)
    #pragma unroll
    for (int i=0;i<4;i++) {
      int r = wr*64 + tm*16 + quad*4 + i;
      float s = lnS[r][0] + lnS[r][1];
      float q = lnQ[r][0] + lnQ[r][1];
      float m = s * (1.f/128.f);
      float var = q * (1.f/128.f) - m*m;
      float rs = rsqrtf(var + LN_EPS);
      int gr = row0 + r;
      if (!SCATTER && gr >= nrows) continue;
      #pragma unroll
      for (int tn=0;tn<4;tn++) {
        float v = (acc[tm][tn][i] - m) * rs * g4[tn] + bb4[tn];
        int c = wc*64 + tn*16 + low;
        if (SCATTER) Hf[r*132 + c] = v;           // stage for seg-reduce
        else         out[(size_t)gr*DD + c] = v;
      }
    }

  if (SCATTER) {
    __syncthreads();
    // segmented sum over src-sorted rows; threads 0-127 rows 0-63, 128-255 rows 64-127
    int col  = tid & 127;
    int rbeg = (tid >> 7) * 64, rend = rbeg + 64;
    float accv = Hf[rbeg*132 + col];
    int cur = sidx_s[rbeg];
    for (int r = rbeg + 1; r < rend; r++) {
      int sv = sidx_s[r];
      float hv = Hf[r*132 + col];
      if (sv != cur) {
        atomicAdd(&out[(size_t)cur*DD + col], accv);
        accv = hv; cur = sv;
      } else accv += hv;
    }
    atomicAdd(&out[(size_t)cur*DD + col], accv);
  }
}

// ---------------------------------------------------------------------------
// out[r] = (x[r] @ W + initv) * rowscale[r]   (64-row tiles, 782 blocks)
// ---------------------------------------------------------------------------
__global__ __launch_bounds__(256)
void gemm_mfma_kernel(const float* __restrict__ x,
                      const short* __restrict__ Wh, const short* __restrict__ Wl,
                      const float* __restrict__ initv, const float* __restrict__ rowscale,
                      float* __restrict__ out, int nrows)
{
  const int tid  = threadIdx.x;
  const int lane = tid & 63, wave = tid >> 6;
  const int wr = wave >> 1, wc = wave & 1;
  const int quad = lane >> 4, low = lane & 15;
  const int row0 = blockIdx.x * 64;

  f32x4 acc[2][4];
  #pragma unroll
  for (int tm=0;tm<2;tm++)
    #pragma unroll
    for (int tn=0;tn<4;tn++) acc[tm][tn] = (f32x4)0.f;

  #pragma unroll
  for (int ks=0;ks<4;ks++) {
    v8s ah[2], al[2], bh[4], bl[4];
    #pragma unroll
    for (int tm=0;tm<2;tm++) {
      int r = row0 + wr*32 + tm*16 + low;
      v8s h = (v8s)0, l = (v8s)0;
      if (r < nrows) {
        const float* p = x + (size_t)r*DD + ks*32 + quad*8;
        float4 f0 = *(const float4*)p;
        float4 f1 = *(const float4*)(p + 4);
        SPLIT8(f0, f1, h, l);
      }
      ah[tm] = h; al[tm] = l;
    }
    #pragma unroll
    for (int tn=0;tn<4;tn++) {
      size_t o = ((size_t)(ks*4+quad)*128 + wc*64 + tn*16 + low)*8;
      bh[tn] = *(const v8s*)(Wh + o);
      bl[tn] = *(const v8s*)(Wl + o);
    }
    #pragma unroll
    for (int tm=0;tm<2;tm++)
      #pragma unroll
      for (int tn=0;tn<4;tn++) { MFMA3(ah[tm], al[tm], bh[tn], bl[tn], acc[tm][tn]); }
  }

  #pragma unroll
  for (int tm=0;tm<2;tm++)
    #pragma unroll
    for (int i=0;i<4;i++) {
      int gr = row0 + wr*32 + tm*16 + quad*4 + i;
      if (gr >= nrows) continue;
      float sc = rowscale ? rowscale[gr] : 1.f;
      #pragma unroll
      for (int tn=0;tn<4;tn++) {
        int c = wc*64 + tn*16 + low;
        float iv = initv ? initv[c] : 0.f;
        out[(size_t)gr*DD + c] = (acc[tm][tn][i] + iv) * sc;
      }
    }
}

// ---------------------------------------------------------------------------
// GCN aggregation on pre-scaled h (h_pre[r] = h[r]*dis[r]):
//   agg_i = dis[i]*(h_pre[i] + sum_{s in N(i)} h_pre[s]) + bias
// Inner loop = pure float2 gather-sum, unrolled x4 for outstanding loads.
// ---------------------------------------------------------------------------
__global__ __launch_bounds__(256)
void gcn_agg_kernel(const float* __restrict__ hpre, const int* __restrict__ rowptr,
                    const int* __restrict__ csr_src, const float* __restrict__ dis,
                    const float* __restrict__ bias,
                    const float* __restrict__ resid, float* __restrict__ out, int mode)
{
  const int wv = threadIdx.x >> 6, lane = threadIdx.x & 63;
  const int i = blockIdx.x*4 + wv;
  if (i >= NN) return;
  const float2* h2 = (const float2*)hpre;
  float2 hv = h2[(size_t)i*64 + lane];
  float ax = hv.x, ay = hv.y;
  const int beg = rowptr[i], end = rowptr[i+1];
  int j = beg;
  for (; j + 4 <= end; j += 4) {
    int s0 = csr_src[j], s1 = csr_src[j+1], s2 = csr_src[j+2], s3 = csr_src[j+3];
    float2 v0 = h2[(size_t)s0*64 + lane];
    float2 v1 = h2[(size_t)s1*64 + lane];
    float2 v2 = h2[(size_t)s2*64 + lane];
    float2 v3 = h2[(size_t)s3*64 + lane];
    ax += (v0.x + v1.x) + (v2.x + v3.x);
    ay += (v0.y + v1.y) + (v2.y + v3.y);
  }
  for (; j < end; j++) {
    int s = csr_src[j];
    float2 v = h2[(size_t)s*64 + lane];
    ax += v.x; ay += v.y;
  }
  float di = dis[i];
  ax = ax*di + bias[2*lane]; ay = ay*di + bias[2*lane+1];
  size_t o = (size_t)i*64 + lane;
  float2 r;
  if (mode == 0) { r.x = leakyf(ax); r.y = leakyf(ay); }
  else { float2 rs = ((const float2*)resid)[o]; r.x = rs.x + ax; r.y = rs.y + ay; }
  ((float2*)out)[o] = r;
}

// ---------------------------------------------------------------------------
// Graph setup
// ---------------------------------------------------------------------------
__global__ void count_kernel(const int* __restrict__ src, const int* __restrict__ dst,
                             int* __restrict__ cnt_src, int* __restrict__ deg_dst)
{
  int e = blockIdx.x*blockDim.x + threadIdx.x;
  if (e < NE) {
    atomicAdd(&cnt_src[src[e]], 1);
    atomicAdd(&deg_dst[dst[e]], 1);
  }
}

__global__ void nodeparams_kernel(const int* __restrict__ deg_dst, const int* __restrict__ cnt_src,
                                  float* __restrict__ dis, float* __restrict__ invcnt)
{
  int i = blockIdx.x*blockDim.x + threadIdx.x;
  if (i < NN) {
    dis[i] = rsqrtf((float)deg_dst[i] + 1.0f);
    invcnt[i] = 1.0f / fmaxf((float)cnt_src[i], 1.0f);
  }
}

__global__ void scan_kernel(const int* __restrict__ deg, int* __restrict__ rowptr,
                            int* __restrict__ nextp)
{
  const int T = 256;
  int tid = threadIdx.x;
  int chunk = (NN + T - 1) / T;
  int begin = tid*chunk, end = begin + chunk; if (end > NN) end = NN; if (begin > NN) begin = NN;
  int s = 0;
  for (int i = begin; i < end; i++) s += deg[i];
  __shared__ int ps[T];
  ps[tid] = s; __syncthreads();
  for (int off = 1; off < T; off <<= 1) {
    int v = 0;
    if (tid >= off) v = ps[tid - off];
    __syncthreads();
    if (tid >= off) ps[tid] += v;
    __syncthreads();
  }
  int base = (tid == 0) ? 0 : ps[tid-1];
  for (int i = begin; i < end; i++) { rowptr[i] = base; nextp[i] = base; base += deg[i]; }
  if (tid == T-1) rowptr[NN] = base;
}

__global__ void fill_kernel(const int* __restrict__ src, const int* __restrict__ dst,
                            int* __restrict__ nextp, int* __restrict__ csr_src)
{
  int e = blockIdx.x*blockDim.x + threadIdx.x;
  if (e < NE) {
    int pos = atomicAdd(&nextp[dst[e]], 1);
    csr_src[pos] = src[e];
  }
}

// src-sorted permutation: eperm[pos] = edge id, srcsorted[pos] = src value
__global__ void fill_src_kernel(const int* __restrict__ src, int* __restrict__ nexts,
                                int* __restrict__ eperm, int* __restrict__ srcsorted)
{
  int e = blockIdx.x*blockDim.x + threadIdx.x;
  if (e < NE) {
    int s = src[e];
    int pos = atomicAdd(&nexts[s], 1);
    eperm[pos] = e;
    srcsorted[pos] = s;
  }
}

__global__ void addmean_kernel(float* __restrict__ hn, const float* __restrict__ nodesum,
                               const float* __restrict__ invcnt)
{
  int t = blockIdx.x*blockDim.x + threadIdx.x;
  if (t < NN*DD) hn[t] += nodesum[t] * invcnt[t >> 7];
}

// ---------------------------------------------------------------------------
// BatchNorm stats + fold into packed hi/lo bf16 conv2 weight
// ---------------------------------------------------------------------------
__global__ __launch_bounds__(256)
void bn_stats_kernel(const float* __restrict__ y, float* __restrict__ sums)
{
  int col = threadIdx.x & 127, grp = threadIdx.x >> 7;
  float s = 0.f, ss = 0.f;
  for (int i = blockIdx.x*2 + grp; i < NN; i += gridDim.x*2) {
    float v = y[(size_t)i*DD + col];
    s += v; ss += v*v;
  }
  __shared__ float ls[256], lss[256];
  ls[threadIdx.x] = s; lss[threadIdx.x] = ss;
  __syncthreads();
  if (grp == 0) {
    atomicAdd(&sums[col],      ls[col]  + ls[col+128]);
    atomicAdd(&sums[DD + col], lss[col] + lss[col+128]);
  }
}

__global__ void bn_fold_kernel(const float* __restrict__ sums, const float* __restrict__ g,
                               const float* __restrict__ b, const float* __restrict__ W2,
                               short* __restrict__ Wfh, short* __restrict__ Wfl,
                               float* __restrict__ cvec)
{
  int col = threadIdx.x;  // 128 threads
  __shared__ float scale[DD], shift[DD];
  float m = sums[col] / (float)NN;
  float var = sums[DD + col] / (float)NN - m*m;
  float is = rsqrtf(var + LN_EPS);
  float sc = is * g[col];
  scale[col] = sc;
  shift[col] = b[col] - m * sc;
  __syncthreads();
  float c = 0.f;
  for (int k = 0; k < DD; k++) {
    float w = W2[k*DD + col];
    short2 t = f2bf2v(w * scale[k]);
    size_t o = ((size_t)(k >> 3)*128 + col)*8 + (k & 7);
    Wfh[o] = t.x; Wfl[o] = t.y;
    c += shift[k] * w;
  }
  cvec[col] = c;
}

// ---------------------------------------------------------------------------
extern "C" void kernel_launch(void* const* d_in, const int* in_sizes, int n_in,
                              void* d_out, int out_size, void* d_ws, size_t ws_size,
                              hipStream_t stream)
{
  const float* node_feat = (const float*)d_in[0];
  const float* edge_feat = (const float*)d_in[1];
  const int*   edge_index = (const int*)d_in[2];
  const int* src = edge_index;
  const int* dst = edge_index + NE;

  const float* enW1 = (const float*)d_in[3];  const float* enb1 = (const float*)d_in[4];
  const float* enW2 = (const float*)d_in[5];  const float* enb2 = (const float*)d_in[6];
  const float* enW3 = (const float*)d_in[7];  const float* enb3 = (const float*)d_in[8];
  const float* enlg = (const float*)d_in[9];  const float* enlb = (const float*)d_in[10];

  const float* eeW1 = (const float*)d_in[11]; const float* eeb1 = (const float*)d_in[12];
  const float* eeW2 = (const float*)d_in[13]; const float* eeb2 = (const float*)d_in[14];
  const float* eeW3 = (const float*)d_in[15]; const float* eeb3 = (const float*)d_in[16];
  const float* eelg = (const float*)d_in[17]; const float* eelb = (const float*)d_in[18];

  const float* procW = (const float*)d_in[19];
  const float* procB = (const float*)d_in[20];
  const float* bnG   = (const float*)d_in[21];
  const float* bnB   = (const float*)d_in[22];

  const float* dW1 = (const float*)d_in[23]; const float* db1 = (const float*)d_in[24];
  const float* dW2 = (const float*)d_in[25]; const float* db2 = (const float*)d_in[26];
  const float* dW3 = (const float*)d_in[27]; const float* db3 = (const float*)d_in[28];
  const float* dlg = (const float*)d_in[29]; const float* dlb = (const float*)d_in[30];

  char* ws = (char*)d_ws;
  size_t off = 0;
  auto alloc = [&](size_t bytes) -> void* {
    void* p = ws + off;
    off = (off + bytes + 255) & ~(size_t)255;
    return p;
  };
  float* hn     = (float*)alloc((size_t)NN*DD*4);
  float* hbuf   = (float*)alloc((size_t)NN*DD*4);
  float* ybuf   = (float*)alloc((size_t)NN*DD*4);
  float* dis    = (float*)alloc(NN*4);
  float* invcnt = (float*)alloc(NN*4);
  float* cvec   = (float*)alloc(DD*4);
  float* bnsums = (float*)alloc(2*DD*4);
  int* deg    = (int*)alloc(NN*4);
  int* cnt    = (int*)alloc(NN*4);
  int* rowptr = (int*)alloc((NN+1)*4);
  int* nextp  = (int*)alloc(NN*4);
  int* srow   = (int*)alloc((NN+1)*4);
  int* nexts  = (int*)alloc(NN*4);
  int* csr    = (int*)alloc((size_t)NE*4);
  int* eperm  = (int*)alloc((size_t)NE*4);
  int* srcsorted = (int*)alloc((size_t)NE*4);
  // packed bf16 hi/lo weight planes
  auto allocW = [&](int kp) { return (short*)alloc((size_t)kp*128*2); };
  short *pN1h=allocW(32),  *pN1l=allocW(32);
  short *pN2h=allocW(128), *pN2l=allocW(128);
  short *pN3h=allocW(128), *pN3l=allocW(128);
  short *pE1h=allocW(32),  *pE1l=allocW(32);
  short *pE2h=allocW(128), *pE2l=allocW(128);
  short *pE3h=allocW(128), *pE3l=allocW(128);
  short *pD1h=allocW(128), *pD1l=allocW(128);
  short *pD2h=allocW(128), *pD2l=allocW(128);
  short *pD3h=allocW(128), *pD3l=allocW(128);
  short *pP0h[5], *pP0l[5];
  for (int s = 0; s < 5; s++) { pP0h[s]=allocW(128); pP0l[s]=allocW(128); }
  short *pWfh=allocW(128), *pWfl=allocW(128);

  (void)hipMemsetAsync(deg, 0, NN*4, stream);
  (void)hipMemsetAsync(cnt, 0, NN*4, stream);
  (void)hipMemsetAsync(hbuf, 0, (size_t)NN*DD*4, stream);   // edge scatter-sum accumulator

  // pack static weights
  const int G32 = (32*128+255)/256, G128 = (128*128+255)/256;
  pack_w_kernel<<<G32, 256, 0, stream>>>(enW1, pN1h, pN1l, 19, 32);
  pack_w_kernel<<<G128,256, 0, stream>>>(enW2, pN2h, pN2l, 128, 128);
  pack_w_kernel<<<G128,256, 0, stream>>>(enW3, pN3h, pN3l, 128, 128);
  pack_w_kernel<<<G32, 256, 0, stream>>>(eeW1, pE1h, pE1l, 4, 32);
  pack_w_kernel<<<G128,256, 0, stream>>>(eeW2, pE2h, pE2l, 128, 128);
  pack_w_kernel<<<G128,256, 0, stream>>>(eeW3, pE3h, pE3l, 128, 128);
  pack_w_kernel<<<G128,256, 0, stream>>>(dW1, pD1h, pD1l, 128, 128);
  pack_w_kernel<<<G128,256, 0, stream>>>(dW2, pD2h, pD2l, 128, 128);
  pack_w_kernel<<<G128,256, 0, stream>>>(dW3, pD3h, pD3l, 128, 128);
  for (int s = 0; s < 5; s++)
    pack_w_kernel<<<G128,256,0,stream>>>(procW + (size_t)(s*2)*DD*DD, pP0h[s], pP0l[s], 128, 128);

  // graph setup: dst-CSR (aggregation) + src-sorted edge permutation (encoder)
  count_kernel<<<(NE+255)/256, 256, 0, stream>>>(src, dst, cnt, deg);
  nodeparams_kernel<<<(NN+255)/256, 256, 0, stream>>>(deg, cnt, dis, invcnt);
  scan_kernel<<<1, 256, 0, stream>>>(deg, rowptr, nextp);
  scan_kernel<<<1, 256, 0, stream>>>(cnt, srow, nexts);
  fill_kernel<<<(NE+255)/256, 256, 0, stream>>>(src, dst, nextp, csr);
  fill_src_kernel<<<(NE+255)/256, 256, 0, stream>>>(src, nexts, eperm, srcsorted);

  const int GN  = (NN + 127) / 128;  // 391
  const int GE  = NE / 128;          // 6250
  const int GG  = (NN + 63) / 64;    // 782

  // encoders
  mlp_mfma_kernel<19, false><<<GN, 256, 0, stream>>>(node_feat, NN,
      pN1h, pN1l, enb1, pN2h, pN2l, enb2, pN3h, pN3l, enb3, enlg, enlb, hn,
      nullptr, nullptr);
  mlp_mfma_kernel<4, true><<<GE, 256, 0, stream>>>(edge_feat, NE,
      pE1h, pE1l, eeb1, pE2h, pE2l, eeb2, pE3h, pE3l, eeb3, eelg, eelb, hbuf,
      srcsorted, eperm);
  addmean_kernel<<<(NN*DD+255)/256, 256, 0, stream>>>(hn, hbuf, invcnt);

  // processor: 5 residual (conv -> leaky -> BN -> conv) steps, BN folded into W2,
  // dis folded into GEMM epilogue (h_pre = h*dis)
  for (int s = 0; s < 5; s++) {
    const float* Wc2 = procW + (size_t)(s*2+1)*DD*DD;
    const float* b0  = procB + (size_t)(s*2+0)*DD;
    const float* b1p = procB + (size_t)(s*2+1)*DD;

    gemm_mfma_kernel<<<GG, 256, 0, stream>>>(hn, pP0h[s], pP0l[s], nullptr, dis, hbuf, NN);
    gcn_agg_kernel<<<(NN+3)/4, 256, 0, stream>>>(hbuf, rowptr, csr, dis, b0, nullptr, ybuf, 0);
    (void)hipMemsetAsync(bnsums, 0, 2*DD*4, stream);
    bn_stats_kernel<<<512, 256, 0, stream>>>(ybuf, bnsums);
    bn_fold_kernel<<<1, 128, 0, stream>>>(bnsums, bnG + s*DD, bnB + s*DD, Wc2, pWfh, pWfl, cvec);
    gemm_mfma_kernel<<<GG, 256, 0, stream>>>(ybuf, pWfh, pWfl, cvec, dis, hbuf, NN);
    gcn_agg_kernel<<<(NN+3)/4, 256, 0, stream>>>(hbuf, rowptr, csr, dis, b1p, hn, hn, 1);
  }

  // decoder -> d_out (fp32)
  mlp_mfma_kernel<128, false><<<GN, 256, 0, stream>>>(hn, NN,
      pD1h, pD1l, db1, pD2h, pD2l, db2, pD3h, pD3l, db3, dlg, dlb, (float*)d_out,
      nullptr, nullptr);
}

// Round 6
// 1718.014 us; speedup vs baseline: 1.9375x; 1.1093x over previous
//
#include <hip/hip_runtime.h>

#define NN 50000
#define NE 800000
#define DD 128
#define LN_EPS 1e-5f

typedef __attribute__((ext_vector_type(8))) short v8s;    // 8 bf16
typedef __attribute__((ext_vector_type(4))) float f32x4;  // MFMA acc

__device__ __forceinline__ float leakyf(float x){ return x > 0.f ? x : 0.05f*x; }
__device__ __forceinline__ short f2bf(float f){
  unsigned u = __float_as_uint(f);
  u = (u + 0x7fffu + ((u >> 16) & 1u)) >> 16;   // RNE
  return (short)u;
}
__device__ __forceinline__ float bf2f(unsigned short h){
  return __uint_as_float(((unsigned)h) << 16);
}
// split fp32 -> {hi, lo}: hi = truncated top-16 (cheap), lo = RNE(residual).
__device__ __forceinline__ short2 f2bf2v(float v){
  unsigned u = __float_as_uint(v);
  short hi = (short)(u >> 16);
  float lo = v - __uint_as_float(u & 0xffff0000u);
  return make_short2(hi, f2bf(lo));
}

// ---------------------------------------------------------------------------
// Pack fp32 W[K][128] -> two bf16 planes Wh/Wl, layout [(k>>3)*128 + n][k&7]
// ---------------------------------------------------------------------------
__global__ void pack_w_kernel(const float* __restrict__ W, short* __restrict__ Wh,
                              short* __restrict__ Wl, int K, int Kp)
{
  int idx = blockIdx.x*256 + threadIdx.x;
  if (idx >= Kp*128) return;
  int k = idx >> 7, n = idx & 127;
  float v = (k < K) ? W[k*128 + n] : 0.f;
  short2 t = f2bf2v(v);
  size_t o = ((size_t)(k >> 3)*128 + n)*8 + (k & 7);
  Wh[o] = t.x; Wl[o] = t.y;
}

#define MFMA3(ah, al, bh, bl, ac) \
  ac = __builtin_amdgcn_mfma_f32_16x16x32_bf16(al, bh, ac, 0,0,0); \
  ac = __builtin_amdgcn_mfma_f32_16x16x32_bf16(ah, bl, ac, 0,0,0); \
  ac = __builtin_amdgcn_mfma_f32_16x16x32_bf16(ah, bh, ac, 0,0,0);

#define SPLIT8(f0, f1, h, l) { \
  short2 t0 = f2bf2v(f0.x), t1 = f2bf2v(f0.y), t2 = f2bf2v(f0.z), t3 = f2bf2v(f0.w); \
  short2 t4 = f2bf2v(f1.x), t5 = f2bf2v(f1.y), t6 = f2bf2v(f1.z), t7 = f2bf2v(f1.w); \
  h[0]=t0.x; l[0]=t0.y; h[1]=t1.x; l[1]=t1.y; h[2]=t2.x; l[2]=t2.y; h[3]=t3.x; l[3]=t3.y; \
  h[4]=t4.x; l[4]=t4.y; h[5]=t5.x; l[5]=t5.y; h[6]=t6.x; l[6]=t6.y; h[7]=t7.x; l[7]=t7.y; }

// ---------------------------------------------------------------------------
// 3-layer MLP + LayerNorm, split-bf16 3-MFMA.
// SCATTER (edge encoder): edges processed in src-sorted order via eperm,
// output seg-reduced per src in LDS, one atomicAdd per (segment, col).
// ---------------------------------------------------------------------------
template<int IN_W, bool SCATTER>
__global__ __launch_bounds__(256)
void mlp_mfma_kernel(const float* __restrict__ x, int nrows,
                     const short* __restrict__ W1h, const short* __restrict__ W1l,
                     const float* __restrict__ b1,
                     const short* __restrict__ W2h, const short* __restrict__ W2l,
                     const float* __restrict__ b2,
                     const short* __restrict__ W3h, const short* __restrict__ W3l,
                     const float* __restrict__ b3,
                     const float* __restrict__ g, const float* __restrict__ bb,
                     float* __restrict__ out,
                     const int* __restrict__ sidx,   // src-sorted src values
                     const int* __restrict__ eperm)  // sorted pos -> edge id
{
  constexpr int L1K = (IN_W + 31) / 32;
  __shared__ __align__(16) short Hboth[2*128*136];   // hi/lo act planes; reused as fp32 seg buffer
  short* Hh = Hboth;
  short* Hl = Hboth + 128*136;
  float* Hf = (float*)Hboth;                          // stride 132 in reduce phase
  __shared__ float lnS[128][2], lnQ[128][2];
  __shared__ int sidx_s[128];
  __shared__ int eperm_s[128];

  const int tid  = threadIdx.x;
  const int lane = tid & 63, wave = tid >> 6;
  const int wr = wave >> 1, wc = wave & 1;
  const int quad = lane >> 4, low = lane & 15;
  const int row0 = blockIdx.x * 128;

  if (SCATTER) {
    if (tid < 128) {
      sidx_s[tid]  = sidx[row0 + tid];   // NE % 128 == 0
      eperm_s[tid] = eperm[row0 + tid];
    }
    __syncthreads();
  }

  f32x4 acc[4][4];

  // ---------------- layer 1 ----------------
  #pragma unroll
  for (int tm=0;tm<4;tm++)
    #pragma unroll
    for (int tn=0;tn<4;tn++) acc[tm][tn] = (f32x4)0.f;

  for (int ks = 0; ks < L1K; ks++) {
    v8s ah[4], al[4], bh[4], bl[4];
    #pragma unroll
    for (int tm=0;tm<4;tm++) {
      int lr = wr*64 + tm*16 + low;
      v8s h = (v8s)0, l = (v8s)0;
      if (SCATTER && IN_W == 4) {
        if (quad == 0) {
          int e = eperm_s[lr];
          float4 f = ((const float4*)x)[e];
          short2 t0 = f2bf2v(f.x), t1 = f2bf2v(f.y), t2 = f2bf2v(f.z), t3 = f2bf2v(f.w);
          h[0]=t0.x; l[0]=t0.y; h[1]=t1.x; l[1]=t1.y;
          h[2]=t2.x; l[2]=t2.y; h[3]=t3.x; l[3]=t3.y;
        }
      } else if (IN_W % 32 == 0) {
        int r = row0 + lr;
        if (r < nrows) {
          const float* p = x + (size_t)r*IN_W + ks*32 + quad*8;
          float4 f0 = *(const float4*)p;
          float4 f1 = *(const float4*)(p + 4);
          SPLIT8(f0, f1, h, l);
        }
      } else {
        int r = row0 + lr;
        #pragma unroll
        for (int j=0;j<8;j++) {
          int k = ks*32 + quad*8 + j;
          if (k < IN_W && r < nrows) {
            short2 t = f2bf2v(x[(size_t)r*IN_W + k]);
            h[j] = t.x; l[j] = t.y;
          }
        }
      }
      ah[tm] = h; al[tm] = l;
    }
    #pragma unroll
    for (int tn=0;tn<4;tn++) {
      size_t o = ((size_t)(ks*4+quad)*128 + wc*64 + tn*16 + low)*8;
      bh[tn] = *(const v8s*)(W1h + o);
      bl[tn] = *(const v8s*)(W1l + o);
    }
    #pragma unroll
    for (int tm=0;tm<4;tm++)
      #pragma unroll
      for (int tn=0;tn<4;tn++) { MFMA3(ah[tm], al[tm], bh[tn], bl[tn], acc[tm][tn]); }
  }
  if (SCATTER) __syncthreads();
  #pragma unroll
  for (int tn=0;tn<4;tn++) {
    float bv = b1[wc*64 + tn*16 + low];
    #pragma unroll
    for (int tm=0;tm<4;tm++)
      #pragma unroll
      for (int i=0;i<4;i++) {
        int idx = (wr*64+tm*16+quad*4+i)*136 + wc*64+tn*16+low;
        short2 t = f2bf2v(leakyf(acc[tm][tn][i] + bv));
        Hh[idx] = t.x; Hl[idx] = t.y;
      }
  }
  __syncthreads();

  // ---------------- layer 2 ----------------
  #pragma unroll
  for (int tm=0;tm<4;tm++)
    #pragma unroll
    for (int tn=0;tn<4;tn++) acc[tm][tn] = (f32x4)0.f;
  #pragma unroll
  for (int ks=0;ks<4;ks++) {
    v8s ah[4], al[4], bh[4], bl[4];
    #pragma unroll
    for (int tm=0;tm<4;tm++) {
      int idx = (wr*64+tm*16+low)*136 + ks*32 + quad*8;
      ah[tm] = *(const v8s*)&Hh[idx];
      al[tm] = *(const v8s*)&Hl[idx];
    }
    #pragma unroll
    for (int tn=0;tn<4;tn++) {
      size_t o = ((size_t)(ks*4+quad)*128 + wc*64 + tn*16 + low)*8;
      bh[tn] = *(const v8s*)(W2h + o);
      bl[tn] = *(const v8s*)(W2l + o);
    }
    #pragma unroll
    for (int tm=0;tm<4;tm++)
      #pragma unroll
      for (int tn=0;tn<4;tn++) { MFMA3(ah[tm], al[tm], bh[tn], bl[tn], acc[tm][tn]); }
  }
  __syncthreads();
  #pragma unroll
  for (int tn=0;tn<4;tn++) {
    float bv = b2[wc*64 + tn*16 + low];
    #pragma unroll
    for (int tm=0;tm<4;tm++)
      #pragma unroll
      for (int i=0;i<4;i++) {
        int idx = (wr*64+tm*16+quad*4+i)*136 + wc*64+tn*16+low;
        short2 t = f2bf2v(leakyf(acc[tm][tn][i] + bv));
        Hh[idx] = t.x; Hl[idx] = t.y;
      }
  }
  __syncthreads();

  // ---------------- layer 3 ----------------
  #pragma unroll
  for (int tm=0;tm<4;tm++)
    #pragma unroll
    for (int tn=0;tn<4;tn++) acc[tm][tn] = (f32x4)0.f;
  #pragma unroll
  for (int ks=0;ks<4;ks++) {
    v8s ah[4], al[4], bh[4], bl[4];
    #pragma unroll
    for (int tm=0;tm<4;tm++) {
      int idx = (wr*64+tm*16+low)*136 + ks*32 + quad*8;
      ah[tm] = *(const v8s*)&Hh[idx];
      al[tm] = *(const v8s*)&Hl[idx];
    }
    #pragma unroll
    for (int tn=0;tn<4;tn++) {
      size_t o = ((size_t)(ks*4+quad)*128 + wc*64 + tn*16 + low)*8;
      bh[tn] = *(const v8s*)(W3h + o);
      bl[tn] = *(const v8s*)(W3l + o);
    }
    #pragma unroll
    for (int tm=0;tm<4;tm++)
      #pragma unroll
      for (int tn=0;tn<4;tn++) { MFMA3(ah[tm], al[tm], bh[tn], bl[tn], acc[tm][tn]); }
  }
  #pragma unroll
  for (int tn=0;tn<4;tn++) {
    float bv = b3[wc*64 + tn*16 + low];
    #pragma unroll
    for (int tm=0;tm<4;tm++)
      #pragma unroll
      for (int i=0;i<4;i++) acc[tm][tn][i] += bv;
  }

  // ---------------- fused LayerNorm ----------------
  #pragma unroll
  for (int tm=0;tm<4;tm++)
    #pragma unroll
    for (int i=0;i<4;i++) {
      float s = acc[tm][0][i] + acc[tm][1][i] + acc[tm][2][i] + acc[tm][3][i];
      float q = acc[tm][0][i]*acc[tm][0][i] + acc[tm][1][i]*acc[tm][1][i]
              + acc[tm][2][i]*acc[tm][2][i] + acc[tm][3][i]*acc[tm][3][i];
      s += __shfl_xor(s, 1); q += __shfl_xor(q, 1);
      s += __shfl_xor(s, 2); q += __shfl_xor(q, 2);
      s += __shfl_xor(s, 4); q += __shfl_xor(q, 4);
      s += __shfl_xor(s, 8); q += __shfl_xor(q, 8);
      if (low == tm*4 + i) {
        int r = wr*64 + tm*16 + quad*4 + i;
        lnS[r][wc] = s; lnQ[r][wc] = q;
      }
    }
  __syncthreads();   // also guarantees all layer-3 H reads are done (Hf reuse below)

  float g4[4], bb4[4];
  #pragma unroll
  for (int tn=0;tn<4;tn++) { int c = wc*64+tn*16+low; g4[tn] = g[c]; bb4[tn] = bb[c]; }

  #pragma unroll
  for (int tm=0;tm<4;tm++)
    #pragma unroll
    for (int i=0;i<4;i++) {
      int r = wr*64 + tm*16 + quad*4 + i;
      float s = lnS[r][0] + lnS[r][1];
      float q = lnQ[r][0] + lnQ[r][1];
      float m = s * (1.f/128.f);
      float var = q * (1.f/128.f) - m*m;
      float rs = rsqrtf(var + LN_EPS);
      int gr = row0 + r;
      if (!SCATTER && gr >= nrows) continue;
      #pragma unroll
      for (int tn=0;tn<4;tn++) {
        float v = (acc[tm][tn][i] - m) * rs * g4[tn] + bb4[tn];
        int c = wc*64 + tn*16 + low;
        if (SCATTER) Hf[r*132 + c] = v;           // stage for seg-reduce
        else         out[(size_t)gr*DD + c] = v;
      }
    }

  if (SCATTER) {
    __syncthreads();
    int col  = tid & 127;
    int rbeg = (tid >> 7) * 64, rend = rbeg + 64;
    float accv = Hf[rbeg*132 + col];
    int cur = sidx_s[rbeg];
    for (int r = rbeg + 1; r < rend; r++) {
      int sv = sidx_s[r];
      float hv = Hf[r*132 + col];
      if (sv != cur) {
        atomicAdd(&out[(size_t)cur*DD + col], accv);
        accv = hv; cur = sv;
      } else accv += hv;
    }
    atomicAdd(&out[(size_t)cur*DD + col], accv);
  }
}

// ---------------------------------------------------------------------------
// outbf[r] = bf16((x[r] @ W + initv) * rowscale[r])   (64-row tiles)
// Output packed bf16 — the aggregation gather table.
// ---------------------------------------------------------------------------
__global__ __launch_bounds__(256)
void gemm_mfma_kernel(const float* __restrict__ x,
                      const short* __restrict__ Wh, const short* __restrict__ Wl,
                      const float* __restrict__ initv, const float* __restrict__ rowscale,
                      unsigned short* __restrict__ outbf, int nrows)
{
  const int tid  = threadIdx.x;
  const int lane = tid & 63, wave = tid >> 6;
  const int wr = wave >> 1, wc = wave & 1;
  const int quad = lane >> 4, low = lane & 15;
  const int row0 = blockIdx.x * 64;

  f32x4 acc[2][4];
  #pragma unroll
  for (int tm=0;tm<2;tm++)
    #pragma unroll
    for (int tn=0;tn<4;tn++) acc[tm][tn] = (f32x4)0.f;

  #pragma unroll
  for (int ks=0;ks<4;ks++) {
    v8s ah[2], al[2], bh[4], bl[4];
    #pragma unroll
    for (int tm=0;tm<2;tm++) {
      int r = row0 + wr*32 + tm*16 + low;
      v8s h = (v8s)0, l = (v8s)0;
      if (r < nrows) {
        const float* p = x + (size_t)r*DD + ks*32 + quad*8;
        float4 f0 = *(const float4*)p;
        float4 f1 = *(const float4*)(p + 4);
        SPLIT8(f0, f1, h, l);
      }
      ah[tm] = h; al[tm] = l;
    }
    #pragma unroll
    for (int tn=0;tn<4;tn++) {
      size_t o = ((size_t)(ks*4+quad)*128 + wc*64 + tn*16 + low)*8;
      bh[tn] = *(const v8s*)(Wh + o);
      bl[tn] = *(const v8s*)(Wl + o);
    }
    #pragma unroll
    for (int tm=0;tm<2;tm++)
      #pragma unroll
      for (int tn=0;tn<4;tn++) { MFMA3(ah[tm], al[tm], bh[tn], bl[tn], acc[tm][tn]); }
  }

  #pragma unroll
  for (int tm=0;tm<2;tm++)
    #pragma unroll
    for (int i=0;i<4;i++) {
      int gr = row0 + wr*32 + tm*16 + quad*4 + i;
      if (gr >= nrows) continue;
      float sc = rowscale ? rowscale[gr] : 1.f;
      #pragma unroll
      for (int tn=0;tn<4;tn++) {
        int c = wc*64 + tn*16 + low;
        float iv = initv ? initv[c] : 0.f;
        outbf[(size_t)gr*DD + c] = (unsigned short)f2bf((acc[tm][tn][i] + iv) * sc);
      }
    }
}

// ---------------------------------------------------------------------------
// GCN aggregation on bf16-packed pre-scaled h (h_pre[r] = h[r]*dis[r]):
//   agg_i = dis[i]*(h_pre[i] + sum_{s in N(i)} h_pre[s]) + bias
// Gather = one uint (2 bf16) per lane per edge; fp32 accumulate; unroll x8.
// ---------------------------------------------------------------------------
__global__ __launch_bounds__(256)
void gcn_agg_kernel(const unsigned* __restrict__ hb, const int* __restrict__ rowptr,
                    const int* __restrict__ csr_src, const float* __restrict__ dis,
                    const float* __restrict__ bias,
                    const float* __restrict__ resid, float* __restrict__ out, int mode)
{
  const int wv = threadIdx.x >> 6, lane = threadIdx.x & 63;
  const int i = blockIdx.x*4 + wv;
  if (i >= NN) return;
  unsigned hv = hb[(size_t)i*64 + lane];
  float ax = bf2f((unsigned short)(hv & 0xffff)), ay = bf2f((unsigned short)(hv >> 16));
  const int beg = rowptr[i], end = rowptr[i+1];
  int j = beg;
  for (; j + 8 <= end; j += 8) {
    unsigned v0 = hb[(size_t)csr_src[j+0]*64 + lane];
    unsigned v1 = hb[(size_t)csr_src[j+1]*64 + lane];
    unsigned v2 = hb[(size_t)csr_src[j+2]*64 + lane];
    unsigned v3 = hb[(size_t)csr_src[j+3]*64 + lane];
    unsigned v4 = hb[(size_t)csr_src[j+4]*64 + lane];
    unsigned v5 = hb[(size_t)csr_src[j+5]*64 + lane];
    unsigned v6 = hb[(size_t)csr_src[j+6]*64 + lane];
    unsigned v7 = hb[(size_t)csr_src[j+7]*64 + lane];
    ax += ((bf2f((unsigned short)(v0 & 0xffff)) + bf2f((unsigned short)(v1 & 0xffff)))
         + (bf2f((unsigned short)(v2 & 0xffff)) + bf2f((unsigned short)(v3 & 0xffff))))
        + ((bf2f((unsigned short)(v4 & 0xffff)) + bf2f((unsigned short)(v5 & 0xffff)))
         + (bf2f((unsigned short)(v6 & 0xffff)) + bf2f((unsigned short)(v7 & 0xffff))));
    ay += ((bf2f((unsigned short)(v0 >> 16)) + bf2f((unsigned short)(v1 >> 16)))
         + (bf2f((unsigned short)(v2 >> 16)) + bf2f((unsigned short)(v3 >> 16))))
        + ((bf2f((unsigned short)(v4 >> 16)) + bf2f((unsigned short)(v5 >> 16)))
         + (bf2f((unsigned short)(v6 >> 16)) + bf2f((unsigned short)(v7 >> 16))));
  }
  for (; j < end; j++) {
    unsigned v = hb[(size_t)csr_src[j]*64 + lane];
    ax += bf2f((unsigned short)(v & 0xffff));
    ay += bf2f((unsigned short)(v >> 16));
  }
  float di = dis[i];
  ax = ax*di + bias[2*lane]; ay = ay*di + bias[2*lane+1];
  size_t o = (size_t)i*64 + lane;
  float2 r;
  if (mode == 0) { r.x = leakyf(ax); r.y = leakyf(ay); }
  else { float2 rs = ((const float2*)resid)[o]; r.x = rs.x + ax; r.y = rs.y + ay; }
  ((float2*)out)[o] = r;
}

// ---------------------------------------------------------------------------
// Graph setup
// ---------------------------------------------------------------------------
__global__ void count_kernel(const int* __restrict__ src, const int* __restrict__ dst,
                             int* __restrict__ cnt_src, int* __restrict__ deg_dst)
{
  int e = blockIdx.x*blockDim.x + threadIdx.x;
  if (e < NE) {
    atomicAdd(&cnt_src[src[e]], 1);
    atomicAdd(&deg_dst[dst[e]], 1);
  }
}

__global__ void nodeparams_kernel(const int* __restrict__ deg_dst, const int* __restrict__ cnt_src,
                                  float* __restrict__ dis, float* __restrict__ invcnt)
{
  int i = blockIdx.x*blockDim.x + threadIdx.x;
  if (i < NN) {
    dis[i] = rsqrtf((float)deg_dst[i] + 1.0f);
    invcnt[i] = 1.0f / fmaxf((float)cnt_src[i], 1.0f);
  }
}

__global__ void scan_kernel(const int* __restrict__ deg, int* __restrict__ rowptr,
                            int* __restrict__ nextp)
{
  const int T = 256;
  int tid = threadIdx.x;
  int chunk = (NN + T - 1) / T;
  int begin = tid*chunk, end = begin + chunk; if (end > NN) end = NN; if (begin > NN) begin = NN;
  int s = 0;
  for (int i = begin; i < end; i++) s += deg[i];
  __shared__ int ps[T];
  ps[tid] = s; __syncthreads();
  for (int off = 1; off < T; off <<= 1) {
    int v = 0;
    if (tid >= off) v = ps[tid - off];
    __syncthreads();
    if (tid >= off) ps[tid] += v;
    __syncthreads();
  }
  int base = (tid == 0) ? 0 : ps[tid-1];
  for (int i = begin; i < end; i++) { rowptr[i] = base; nextp[i] = base; base += deg[i]; }
  if (tid == T-1) rowptr[NN] = base;
}

__global__ void fill_kernel(const int* __restrict__ src, const int* __restrict__ dst,
                            int* __restrict__ nextp, int* __restrict__ csr_src)
{
  int e = blockIdx.x*blockDim.x + threadIdx.x;
  if (e < NE) {
    int pos = atomicAdd(&nextp[dst[e]], 1);
    csr_src[pos] = src[e];
  }
}

__global__ void fill_src_kernel(const int* __restrict__ src, int* __restrict__ nexts,
                                int* __restrict__ eperm, int* __restrict__ srcsorted)
{
  int e = blockIdx.x*blockDim.x + threadIdx.x;
  if (e < NE) {
    int s = src[e];
    int pos = atomicAdd(&nexts[s], 1);
    eperm[pos] = e;
    srcsorted[pos] = s;
  }
}

__global__ void addmean_kernel(float* __restrict__ hn, const float* __restrict__ nodesum,
                               const float* __restrict__ invcnt)
{
  int t = blockIdx.x*blockDim.x + threadIdx.x;
  if (t < NN*DD) hn[t] += nodesum[t] * invcnt[t >> 7];
}

// ---------------------------------------------------------------------------
// BatchNorm stats + fold into packed hi/lo bf16 conv2 weight
// ---------------------------------------------------------------------------
__global__ __launch_bounds__(256)
void bn_stats_kernel(const float* __restrict__ y, float* __restrict__ sums)
{
  int col = threadIdx.x & 127, grp = threadIdx.x >> 7;
  float s = 0.f, ss = 0.f;
  for (int i = blockIdx.x*2 + grp; i < NN; i += gridDim.x*2) {
    float v = y[(size_t)i*DD + col];
    s += v; ss += v*v;
  }
  __shared__ float ls[256], lss[256];
  ls[threadIdx.x] = s; lss[threadIdx.x] = ss;
  __syncthreads();
  if (grp == 0) {
    atomicAdd(&sums[col],      ls[col]  + ls[col+128]);
    atomicAdd(&sums[DD + col], lss[col] + lss[col+128]);
  }
}

__global__ void bn_fold_kernel(const float* __restrict__ sums, const float* __restrict__ g,
                               const float* __restrict__ b, const float* __restrict__ W2,
                               short* __restrict__ Wfh, short* __restrict__ Wfl,
                               float* __restrict__ cvec)
{
  int col = threadIdx.x;  // 128 threads
  __shared__ float scale[DD], shift[DD];
  float m = sums[col] / (float)NN;
  float var = sums[DD + col] / (float)NN - m*m;
  float is = rsqrtf(var + LN_EPS);
  float sc = is * g[col];
  scale[col] = sc;
  shift[col] = b[col] - m * sc;
  __syncthreads();
  float c = 0.f;
  for (int k = 0; k < DD; k++) {
    float w = W2[k*DD + col];
    short2 t = f2bf2v(w * scale[k]);
    size_t o = ((size_t)(k >> 3)*128 + col)*8 + (k & 7);
    Wfh[o] = t.x; Wfl[o] = t.y;
    c += shift[k] * w;
  }
  cvec[col] = c;
}

// ---------------------------------------------------------------------------
extern "C" void kernel_launch(void* const* d_in, const int* in_sizes, int n_in,
                              void* d_out, int out_size, void* d_ws, size_t ws_size,
                              hipStream_t stream)
{
  const float* node_feat = (const float*)d_in[0];
  const float* edge_feat = (const float*)d_in[1];
  const int*   edge_index = (const int*)d_in[2];
  const int* src = edge_index;
  const int* dst = edge_index + NE;

  const float* enW1 = (const float*)d_in[3];  const float* enb1 = (const float*)d_in[4];
  const float* enW2 = (const float*)d_in[5];  const float* enb2 = (const float*)d_in[6];
  const float* enW3 = (const float*)d_in[7];  const float* enb3 = (const float*)d_in[8];
  const float* enlg = (const float*)d_in[9];  const float* enlb = (const float*)d_in[10];

  const float* eeW1 = (const float*)d_in[11]; const float* eeb1 = (const float*)d_in[12];
  const float* eeW2 = (const float*)d_in[13]; const float* eeb2 = (const float*)d_in[14];
  const float* eeW3 = (const float*)d_in[15]; const float* eeb3 = (const float*)d_in[16];
  const float* eelg = (const float*)d_in[17]; const float* eelb = (const float*)d_in[18];

  const float* procW = (const float*)d_in[19];
  const float* procB = (const float*)d_in[20];
  const float* bnG   = (const float*)d_in[21];
  const float* bnB   = (const float*)d_in[22];

  const float* dW1 = (const float*)d_in[23]; const float* db1 = (const float*)d_in[24];
  const float* dW2 = (const float*)d_in[25]; const float* db2 = (const float*)d_in[26];
  const float* dW3 = (const float*)d_in[27]; const float* db3 = (const float*)d_in[28];
  const float* dlg = (const float*)d_in[29]; const float* dlb = (const float*)d_in[30];

  char* ws = (char*)d_ws;
  size_t off = 0;
  auto alloc = [&](size_t bytes) -> void* {
    void* p = ws + off;
    off = (off + bytes + 255) & ~(size_t)255;
    return p;
  };
  float* hn     = (float*)alloc((size_t)NN*DD*4);
  float* ybuf   = (float*)alloc((size_t)NN*DD*4);
  float* esum   = (float*)alloc((size_t)NN*DD*4);   // edge scatter-sum accumulator
  unsigned short* hbf = (unsigned short*)alloc((size_t)NN*DD*2);  // bf16 gather table
  float* dis    = (float*)alloc(NN*4);
  float* invcnt = (float*)alloc(NN*4);
  float* cvec   = (float*)alloc(DD*4);
  float* bnsums = (float*)alloc(2*DD*4);
  int* deg    = (int*)alloc(NN*4);
  int* cnt    = (int*)alloc(NN*4);
  int* rowptr = (int*)alloc((NN+1)*4);
  int* nextp  = (int*)alloc(NN*4);
  int* srow   = (int*)alloc((NN+1)*4);
  int* nexts  = (int*)alloc(NN*4);
  int* csr    = (int*)alloc((size_t)NE*4);
  int* eperm  = (int*)alloc((size_t)NE*4);
  int* srcsorted = (int*)alloc((size_t)NE*4);
  auto allocW = [&](int kp) { return (short*)alloc((size_t)kp*128*2); };
  short *pN1h=allocW(32),  *pN1l=allocW(32);
  short *pN2h=allocW(128), *pN2l=allocW(128);
  short *pN3h=allocW(128), *pN3l=allocW(128);
  short *pE1h=allocW(32),  *pE1l=allocW(32);
  short *pE2h=allocW(128), *pE2l=allocW(128);
  short *pE3h=allocW(128), *pE3l=allocW(128);
  short *pD1h=allocW(128), *pD1l=allocW(128);
  short *pD2h=allocW(128), *pD2l=allocW(128);
  short *pD3h=allocW(128), *pD3l=allocW(128);
  short *pP0h[5], *pP0l[5];
  for (int s = 0; s < 5; s++) { pP0h[s]=allocW(128); pP0l[s]=allocW(128); }
  short *pWfh=allocW(128), *pWfl=allocW(128);

  (void)hipMemsetAsync(deg, 0, NN*4, stream);
  (void)hipMemsetAsync(cnt, 0, NN*4, stream);
  (void)hipMemsetAsync(esum, 0, (size_t)NN*DD*4, stream);

  // pack static weights
  const int G32 = (32*128+255)/256, G128 = (128*128+255)/256;
  pack_w_kernel<<<G32, 256, 0, stream>>>(enW1, pN1h, pN1l, 19, 32);
  pack_w_kernel<<<G128,256, 0, stream>>>(enW2, pN2h, pN2l, 128, 128);
  pack_w_kernel<<<G128,256, 0, stream>>>(enW3, pN3h, pN3l, 128, 128);
  pack_w_kernel<<<G32, 256, 0, stream>>>(eeW1, pE1h, pE1l, 4, 32);
  pack_w_kernel<<<G128,256, 0, stream>>>(eeW2, pE2h, pE2l, 128, 128);
  pack_w_kernel<<<G128,256, 0, stream>>>(eeW3, pE3h, pE3l, 128, 128);
  pack_w_kernel<<<G128,256, 0, stream>>>(dW1, pD1h, pD1l, 128, 128);
  pack_w_kernel<<<G128,256, 0, stream>>>(dW2, pD2h, pD2l, 128, 128);
  pack_w_kernel<<<G128,256, 0, stream>>>(dW3, pD3h, pD3l, 128, 128);
  for (int s = 0; s < 5; s++)
    pack_w_kernel<<<G128,256,0,stream>>>(procW + (size_t)(s*2)*DD*DD, pP0h[s], pP0l[s], 128, 128);

  // graph setup
  count_kernel<<<(NE+255)/256, 256, 0, stream>>>(src, dst, cnt, deg);
  nodeparams_kernel<<<(NN+255)/256, 256, 0, stream>>>(deg, cnt, dis, invcnt);
  scan_kernel<<<1, 256, 0, stream>>>(deg, rowptr, nextp);
  scan_kernel<<<1, 256, 0, stream>>>(cnt, srow, nexts);
  fill_kernel<<<(NE+255)/256, 256, 0, stream>>>(src, dst, nextp, csr);
  fill_src_kernel<<<(NE+255)/256, 256, 0, stream>>>(src, nexts, eperm, srcsorted);

  const int GN  = (NN + 127) / 128;  // 391
  const int GE  = NE / 128;          // 6250
  const int GG  = (NN + 63) / 64;    // 782

  // encoders
  mlp_mfma_kernel<19, false><<<GN, 256, 0, stream>>>(node_feat, NN,
      pN1h, pN1l, enb1, pN2h, pN2l, enb2, pN3h, pN3l, enb3, enlg, enlb, hn,
      nullptr, nullptr);
  mlp_mfma_kernel<4, true><<<GE, 256, 0, stream>>>(edge_feat, NE,
      pE1h, pE1l, eeb1, pE2h, pE2l, eeb2, pE3h, pE3l, eeb3, eelg, eelb, esum,
      srcsorted, eperm);
  addmean_kernel<<<(NN*DD+255)/256, 256, 0, stream>>>(hn, esum, invcnt);

  // processor: 5 residual (conv -> leaky -> BN -> conv) steps; BN folded into W2,
  // dis folded into GEMM epilogue, gather table in bf16.
  for (int s = 0; s < 5; s++) {
    const float* Wc2 = procW + (size_t)(s*2+1)*DD*DD;
    const float* b0  = procB + (size_t)(s*2+0)*DD;
    const float* b1p = procB + (size_t)(s*2+1)*DD;

    gemm_mfma_kernel<<<GG, 256, 0, stream>>>(hn, pP0h[s], pP0l[s], nullptr, dis, hbf, NN);
    gcn_agg_kernel<<<(NN+3)/4, 256, 0, stream>>>((const unsigned*)hbf, rowptr, csr, dis,
                                                 b0, nullptr, ybuf, 0);
    (void)hipMemsetAsync(bnsums, 0, 2*DD*4, stream);
    bn_stats_kernel<<<512, 256, 0, stream>>>(ybuf, bnsums);
    bn_fold_kernel<<<1, 128, 0, stream>>>(bnsums, bnG + s*DD, bnB + s*DD, Wc2, pWfh, pWfl, cvec);
    gemm_mfma_kernel<<<GG, 256, 0, stream>>>(ybuf, pWfh, pWfl, cvec, dis, hbf, NN);
    gcn_agg_kernel<<<(NN+3)/4, 256, 0, stream>>>((const unsigned*)hbf, rowptr, csr, dis,
                                                 b1p, hn, hn, 1);
  }

  // decoder -> d_out (fp32)
  mlp_mfma_kernel<128, false><<<GN, 256, 0, stream>>>(hn, NN,
      pD1h, pD1l, db1, pD2h, pD2l, db2, pD3h, pD3l, db3, dlg, dlb, (float*)d_out,
      nullptr, nullptr);
}